// Round 10
// baseline (2583.352 us; speedup 1.0000x reference)
//
#include <hip/hip_runtime.h>

typedef unsigned short bf16;
typedef __attribute__((ext_vector_type(8))) short bf16x8;
typedef __attribute__((ext_vector_type(4))) float f32x4;
typedef unsigned short u16x4 __attribute__((ext_vector_type(4)));

#define DEVFN static __device__ __forceinline__

#define NL 12

#define VMW(N) asm volatile("s_waitcnt vmcnt(" #N ")" ::: "memory")
#define RBAR() asm volatile("s_barrier" ::: "memory")
#define SCHB() __builtin_amdgcn_sched_barrier(0)

DEVFN unsigned short f2bf(float f) {
  union { float f; unsigned u; } v; v.f = f;
  unsigned u = v.u;
  unsigned r = (u + 0x7fffu + ((u >> 16) & 1u)) >> 16;  // RNE
  return (unsigned short)r;
}
DEVFN float bf2f(unsigned short h) {
  union { unsigned u; float f; } v; v.u = ((unsigned)h) << 16; return v.f;
}
// truncation hi/lo split: 4 ALU ops, pair error ~2^-18
DEVFN void tsplit(float v, unsigned short& h, unsigned short& l) {
  union { float f; unsigned u; } a; a.f = v;
  h = (unsigned short)(a.u >> 16);
  union { float f; unsigned u; } b; b.u = a.u & 0xffff0000u;
  union { float f; unsigned u; } c; c.f = v - b.f;
  l = (unsigned short)(c.u >> 16);
}
// async global->LDS, 16B per lane; dest = wave-uniform base + lane*16
DEVFN void gll16(const bf16* g, bf16* l) {
  __builtin_amdgcn_global_load_lds(
      (const __attribute__((address_space(1))) unsigned int*)g,
      (__attribute__((address_space(3))) unsigned int*)l, 16, 0, 0);
}

#define MFMA_BF16(a, b, c) __builtin_amdgcn_mfma_f32_16x16x32_bf16((a), (b), (c), 0, 0, 0)

// ---------------------------------------------------------------------------
// Weight prep (unchanged). Per-layer bf16 block (1310720), bias block (2304).
// ---------------------------------------------------------------------------
__global__ void prep_weights(const float* __restrict__ Wq, const float* __restrict__ bq,
                             const float* __restrict__ Wk, const float* __restrict__ bk,
                             const float* __restrict__ Wv, const float* __restrict__ bv,
                             const float* __restrict__ Wm, const float* __restrict__ bm,
                             const float* __restrict__ W1, const float* __restrict__ b1,
                             const float* __restrict__ gm, const float* __restrict__ bt,
                             const float* __restrict__ W2, const float* __restrict__ b2,
                             bf16* __restrict__ Wbf, float* __restrict__ bias)
{
  int l = blockIdx.y;
  bf16* wl = Wbf + (size_t)l * 1310720;
  float* bl = bias + l * 2304;
  int idx = blockIdx.x * blockDim.x + threadIdx.x;
  if (idx >= 1310720 + 2304) return;
  const float INV = 1.0f / sqrtf(1.0f + 1e-5f);
  const float Cs = 0.18033688011112042f;  // log2(e)/8

  float w = 0.f;
  int lo = 0;
  if (idx < 393216) {                         // Wqkv
    int j = idx; lo = (j >= 196608); j -= lo * 196608;
    int t = j >> 16;
    int p = (j >> 8) & 255;
    int k = j & 255;
    int c = ((p & 63) << 2) | (p >> 6);       // p = h*64+i -> c = i*4+h
    const float* W = (t == 0) ? Wq : (t == 1) ? Wk : Wv;
    w = W[(size_t)l * 65536 + c * 256 + k];
    if (t == 0) w *= Cs;
  } else if (idx < 524288) {                  // Wm (cols permuted)
    int j = idx - 393216; lo = (j >= 65536); j -= lo * 65536;
    int o = j >> 8, p = j & 255;
    int c = ((p & 63) << 2) | (p >> 6);
    w = Wm[(size_t)l * 65536 + o * 256 + c];
  } else if (idx < 1048576) {                 // W1
    int j = idx - 524288; lo = (j >= 262144); j &= 262143;
    w = W1[(size_t)l * 262144 + j];
  } else if (idx < 1310720) {                 // W2
    int j = idx - 1048576; lo = (j >= 131072); j &= 131071;
    w = W2[(size_t)l * 131072 + j];
  } else {
    int j = idx - 1310720;
    if (j < 768) {
      int t = j >> 8, p = j & 255;
      int c = ((p & 63) << 2) | (p >> 6);
      const float* bsrc = (t == 0) ? bq : (t == 1) ? bk : bv;
      bl[j] = bsrc[l * 256 + c] * ((t == 0) ? Cs : 1.0f);
    } else if (j < 1024) {
      bl[j] = bm[l * 256 + (j - 768)];
    } else if (j < 1536) {
      bl[j] = gm[l * 512 + (j - 1024)] * INV;
    } else if (j < 2048) {
      int o = j - 1536;
      bl[j] = gm[l * 512 + o] * INV * b1[l * 512 + o] + bt[l * 512 + o];
    } else {
      bl[j] = b2[l * 256 + (j - 2048)];
    }
    return;
  }
  unsigned short hi = f2bf(w);
  wl[idx] = lo ? f2bf(w - bf2f(hi)) : hi;
}

// ---------------------------------------------------------------------------
__global__ void transpose_in(const float* __restrict__ s0, const float* __restrict__ s1,
                             float* __restrict__ Dm, bf16* __restrict__ Hin,
                             bf16* __restrict__ XMl)
{
  __shared__ float t[32][33];
  int db = blockIdx.z;
  int dsc = db >> 1, bi = db & 1;
  const float* src = dsc ? s1 : s0;
  int n0 = blockIdx.x * 32, d0 = blockIdx.y * 32;
  int tx = threadIdx.x, ty = threadIdx.y;
  #pragma unroll
  for (int i = 0; i < 32; i += 8)
    t[ty + i][tx] = src[(size_t)(bi * 256 + d0 + ty + i) * 2048 + n0 + tx];
  __syncthreads();
  #pragma unroll
  for (int i = 0; i < 32; i += 8) {
    size_t xi = (size_t)db * 2048 + n0 + ty + i;
    float v = t[tx][ty + i];
    Dm[xi * 256 + d0 + tx] = v;
    unsigned short hi, lo;
    tsplit(v, hi, lo);
    Hin[xi * 512 + d0 + tx] = hi;
    XMl[xi * 512 + d0 + tx] = lo;
  }
}

__global__ void transpose_out(const float* __restrict__ Dm, float* __restrict__ out)
{
  __shared__ float t[32][33];
  int db = blockIdx.z;
  int n0 = blockIdx.x * 32, d0 = blockIdx.y * 32;
  int tx = threadIdx.x, ty = threadIdx.y;
  #pragma unroll
  for (int i = 0; i < 32; i += 8)
    t[ty + i][tx] = Dm[((size_t)db * 2048 + n0 + ty + i) * 256 + d0 + tx];
  __syncthreads();
  #pragma unroll
  for (int i = 0; i < 32; i += 8)
    out[(size_t)(db * 256 + d0 + ty + i) * 2048 + n0 + tx] = t[tx][ty + i];
}

// ---------------------------------------------------------------------------
// 3-term split GEMM, tile 128xNT (NT=128 QKV/MLP1, NT=64 merge/MLP2), BK=32,
// 4 waves (2x2). Double-buffered global_load_lds, counted vmcnt + raw bars.
// Granule-major LDS slots (conflict-free): read addr
// (row>>4)*512 + g*128 + (row&15)*8 -> each 8-lane phase hits 8 distinct
// 16B bank-quads. Staging source: lane -> row (lane&15), granule (lane>>4).
// ---------------------------------------------------------------------------
DEVFN int gidx(int row, int g) { return ((row >> 4) << 9) + (g << 7) + ((row & 15) << 3); }

template<int EPI, int NT>
__global__ __launch_bounds__(256, (NT == 128) ? 2 : 3) void gemm3(
    const bf16* __restrict__ Ah, int lda,
    const bf16* __restrict__ Al, int ldal,
    const bf16* __restrict__ Wh, const bf16* __restrict__ Wl, int K,
    const float* __restrict__ b0, const float* __restrict__ b1,
    bf16* __restrict__ o0, bf16* __restrict__ o1,
    bf16* __restrict__ o2, bf16* __restrict__ o3,
    bf16* __restrict__ o4, bf16* __restrict__ o5,
    float* __restrict__ of)
{
  constexpr int NFR = NT / 32;
  __shared__ bf16 AsH[2][4096];
  __shared__ bf16 AsL[2][4096];
  __shared__ bf16 BsH[2][NT * 32];
  __shared__ bf16 BsL[2][NT * 32];
  int tid = threadIdx.x, lane = tid & 63, wid = tid >> 6;
  int wr = wid >> 1, wc = wid & 1;
  int m0 = blockIdx.x * 128, n0 = blockIdx.y * NT;

  // granule-major staging source
  int srow = lane & 15, sg = (lane >> 4) << 3;
  const bf16* A0h = Ah + (size_t)(m0 + wid * 16 + srow) * lda + sg;
  const bf16* A0l = Al + (size_t)(m0 + wid * 16 + srow) * ldal + sg;
  const bf16* B0h = Wh + (size_t)(n0 + wid * 16 + srow) * K + sg;
  const bf16* B0l = Wl + (size_t)(n0 + wid * 16 + srow) * K + sg;
  size_t a64h = (size_t)64 * lda, a64l = (size_t)64 * ldal, b64 = (size_t)64 * K;

  auto issue = [&](int k0, int b) {
    gll16(A0h + k0, &AsH[b][wid * 512]);
    gll16(A0h + a64h + k0, &AsH[b][2048 + wid * 512]);
    gll16(A0l + k0, &AsL[b][wid * 512]);
    gll16(A0l + a64l + k0, &AsL[b][2048 + wid * 512]);
    gll16(B0h + k0, &BsH[b][wid * 512]);
    gll16(B0l + k0, &BsL[b][wid * 512]);
    if constexpr (NT == 128) {
      gll16(B0h + b64 + k0, &BsH[b][2048 + wid * 512]);
      gll16(B0l + b64 + k0, &BsL[b][2048 + wid * 512]);
    }
  };

  f32x4 zero = {0.f, 0.f, 0.f, 0.f};
  f32x4 acc[4][NFR];
  #pragma unroll
  for (int i = 0; i < 4; i++)
    #pragma unroll
    for (int j = 0; j < NFR; j++) acc[i][j] = zero;

  int fr = lane & 15, g = lane >> 4;
  int cb = wc * (NT / 2);
  int nk = K >> 5;

  issue(0, 0);
  for (int ks = 0; ks < nk; ks++) {
    int cur = ks & 1;
    if (ks + 1 < nk) {
      issue((ks + 1) << 5, cur ^ 1);
      if constexpr (NT == 128) VMW(8); else VMW(6);
    } else {
      VMW(0);
    }
    RBAR(); SCHB();
    bf16x8 afh[4], afl[4], bfh[NFR], bfl[NFR];
    #pragma unroll
    for (int i = 0; i < 4; i++) {
      afh[i] = *(const bf16x8*)(&AsH[cur][gidx(wr * 64 + i * 16 + fr, g)]);
      afl[i] = *(const bf16x8*)(&AsL[cur][gidx(wr * 64 + i * 16 + fr, g)]);
    }
    #pragma unroll
    for (int i = 0; i < NFR; i++) {
      bfh[i] = *(const bf16x8*)(&BsH[cur][gidx(cb + i * 16 + fr, g)]);
      bfl[i] = *(const bf16x8*)(&BsL[cur][gidx(cb + i * 16 + fr, g)]);
    }
    #pragma unroll
    for (int mi = 0; mi < 4; mi++)
      #pragma unroll
      for (int ni = 0; ni < NFR; ni++) {
        acc[mi][ni] = MFMA_BF16(afh[mi], bfh[ni], acc[mi][ni]);
        acc[mi][ni] = MFMA_BF16(afl[mi], bfh[ni], acc[mi][ni]);
        acc[mi][ni] = MFMA_BF16(afh[mi], bfl[ni], acc[mi][ni]);
      }
    RBAR();
  }

  #pragma unroll
  for (int mi = 0; mi < 4; mi++) {
    #pragma unroll
    for (int ni = 0; ni < NFR; ni++) {
      int mrow = m0 + wr * 64 + mi * 16 + ((lane >> 4) << 2);
      int ocol = n0 + cb + ni * 16 + fr;
      if constexpr (EPI == 0) {          // fused QKV
        float bb = b0[ocol];
        if (ocol < 512) {
          bf16* Dh = (ocol < 256) ? o0 : o2;
          bf16* Dl = (ocol < 256) ? o1 : o3;
          int oo = ocol & 255;
          #pragma unroll
          for (int r = 0; r < 4; r++) {
            unsigned short hi, lo;
            tsplit(acc[mi][ni][r] + bb, hi, lo);
            Dh[(size_t)(mrow + r) * 256 + oo] = hi;
            Dl[(size_t)(mrow + r) * 256 + oo] = lo;
          }
        } else {
          int c = ocol - 512;
          int dbi = mrow >> 11, nn = mrow & 2047;
          u16x4 ph, pl;
          #pragma unroll
          for (int r = 0; r < 4; r++) {
            unsigned short hi, lo;
            tsplit(acc[mi][ni][r] + bb, hi, lo);
            ph[r] = hi; pl[r] = lo;
          }
          *(u16x4*)(&o4[((size_t)dbi * 256 + c) * 2048 + nn]) = ph;
          *(u16x4*)(&o5[((size_t)dbi * 256 + c) * 2048 + nn]) = pl;
        }
      } else if constexpr (EPI == 2) {   // merge -> msg hi+lo
        float bb = b0[ocol];
        #pragma unroll
        for (int r = 0; r < 4; r++) {
          unsigned short hi, lo;
          tsplit(acc[mi][ni][r] + bb, hi, lo);
          o0[(size_t)(mrow + r) * 512 + 256 + ocol] = hi;
          o1[(size_t)(mrow + r) * 512 + 256 + ocol] = lo;
        }
      } else if constexpr (EPI == 3) {   // BN+ReLU hi+lo
        float ge = b0[ocol], be = b1[ocol];
        #pragma unroll
        for (int r = 0; r < 4; r++) {
          unsigned short hi, lo;
          tsplit(fmaxf(ge * acc[mi][ni][r] + be, 0.f), hi, lo);
          o0[(size_t)(mrow + r) * 512 + ocol] = hi;
          o1[(size_t)(mrow + r) * 512 + ocol] = lo;
        }
      } else {                           // EPI 4: residual
        float bb = b0[ocol];
        #pragma unroll
        for (int r = 0; r < 4; r++) {
          size_t ix = (size_t)(mrow + r) * 256 + ocol;
          float d = of[ix] + acc[mi][ni][r] + bb;
          of[ix] = d;
          unsigned short hi, lo;
          tsplit(d, hi, lo);
          o0[(size_t)(mrow + r) * 512 + ocol] = hi;
          o1[(size_t)(mrow + r) * 512 + ocol] = lo;
        }
      }
    }
  }
}

// ---------------------------------------------------------------------------
// Flash attention, split-KV (2 halves), 3-term QK^T/PV, 3-phase pipelined.
// NEW: 4 waves x 32 rows (was 8 x 16) -- B-fragment (K/V) LDS reads per wave
// are row-count-invariant, so reads-per-output halve (LDS pipe was binding).
// ---------------------------------------------------------------------------
DEVFN int swz(int row, int col) { return row * 64 + (col ^ ((row & 7) << 3)); }

__global__ __launch_bounds__(256) void attn3s(
    const bf16* __restrict__ Qh, const bf16* __restrict__ Ql,
    const bf16* __restrict__ Kh, const bf16* __restrict__ Kl,
    const bf16* __restrict__ Vth, const bf16* __restrict__ Vtl,
    float* __restrict__ Pacc, float* __restrict__ Ml, int cross)
{
  __shared__ bf16 Ksh[64 * 64];
  __shared__ bf16 Ksl[64 * 64];
  __shared__ bf16 Vsh[64 * 64];
  __shared__ bf16 Vsl[64 * 64];
  __shared__ bf16 Psh[4][2048];
  __shared__ bf16 Psl[4][2048];
  int tid = threadIdx.x, lane = tid & 63, w = tid >> 6;  // 4 waves
  int inst = blockIdx.y;
  int half = blockIdx.z;
  int db = inst >> 2, hd = inst & 3;
  int dsc = db >> 1, bi = db & 1;
  int sdb = (cross ? (1 - dsc) : dsc) * 2 + bi;
  size_t xq = (size_t)db * 2048;
  size_t xs = (size_t)sdb * 2048 + half * 1024;
  int n0 = blockIdx.x * 128;

  int fr = lane & 15, kof = (lane >> 4) << 3;

  // Q fragments hi/lo (2 row-tiles x 2 k-frags): direct global -> registers
  bf16x8 aqh[2][2], aql[2][2];
  #pragma unroll
  for (int mi = 0; mi < 2; mi++)
    #pragma unroll
    for (int kf = 0; kf < 2; kf++) {
      size_t g = (xq + n0 + w * 32 + mi * 16 + fr) * 256 + hd * 64 + kf * 32 + kof;
      aqh[mi][kf] = *(const bf16x8*)(Qh + g);
      aql[mi][kf] = *(const bf16x8*)(Ql + g);
    }

  f32x4 zero = {0.f, 0.f, 0.f, 0.f};
  f32x4 oacc[2][4];
  #pragma unroll
  for (int mi = 0; mi < 2; mi++)
    #pragma unroll
    for (int ni = 0; ni < 4; ni++) oacc[mi][ni] = zero;
  float mrun[2][4], lrun[2][4];
  #pragma unroll
  for (int mi = 0; mi < 2; mi++)
    #pragma unroll
    for (int r = 0; r < 4; r++) { mrun[mi][r] = -3.0e38f; lrun[mi][r] = 0.f; }

  bf16x8 vone;
  #pragma unroll
  for (int i = 0; i < 8; i++) vone[i] = (short)0x3F80;  // bf16 1.0

  // staging: 4 waves x 2 chunks of 8 rows; pre-swizzled source granule
  int lrow = lane >> 3;
  int g8 = ((lane & 7) ^ (lrow & 7)) << 3;
  int kr0 = w * 8 + lrow;        // rows 0..31
  int kr1 = 32 + w * 8 + lrow;   // rows 32..63
  const bf16* Kh0 = Kh + (xs + kr0) * 256 + hd * 64 + g8;
  const bf16* Kh1 = Kh + (xs + kr1) * 256 + hd * 64 + g8;
  const bf16* Kl0 = Kl + (xs + kr0) * 256 + hd * 64 + g8;
  const bf16* Kl1 = Kl + (xs + kr1) * 256 + hd * 64 + g8;
  const bf16* Vh0 = Vth + ((size_t)sdb * 256 + hd * 64 + kr0) * 2048 + half * 1024 + g8;
  const bf16* Vh1 = Vth + ((size_t)sdb * 256 + hd * 64 + kr1) * 2048 + half * 1024 + g8;
  const bf16* Vl0 = Vtl + ((size_t)sdb * 256 + hd * 64 + kr0) * 2048 + half * 1024 + g8;
  const bf16* Vl1 = Vtl + ((size_t)sdb * 256 + hd * 64 + kr1) * 2048 + half * 1024 + g8;

  auto issueK = [&](int t) {
    gll16(Kh0 + (size_t)t * 16384, Ksh + w * 512);
    gll16(Kh1 + (size_t)t * 16384, Ksh + 2048 + w * 512);
    gll16(Kl0 + (size_t)t * 16384, Ksl + w * 512);
    gll16(Kl1 + (size_t)t * 16384, Ksl + 2048 + w * 512);
  };
  auto issueV = [&](int t) {
    gll16(Vh0 + t * 64, Vsh + w * 512);
    gll16(Vh1 + t * 64, Vsh + 2048 + w * 512);
    gll16(Vl0 + t * 64, Vsl + w * 512);
    gll16(Vl1 + t * 64, Vsl + 2048 + w * 512);
  };

  issueK(0);
  issueV(0);

  for (int t = 0; t < 16; t++) {
    VMW(4);            // K(t) landed (V(t) may still be in flight)
    RBAR(); SCHB();

    // ---- QK^T (3-term, 2 row-tiles) ----
    f32x4 sacc[2][4];
    #pragma unroll
    for (int mi = 0; mi < 2; mi++)
      #pragma unroll
      for (int ni = 0; ni < 4; ni++) sacc[mi][ni] = zero;
    __builtin_amdgcn_s_setprio(1);
    #pragma unroll
    for (int kf = 0; kf < 2; kf++) {
      #pragma unroll
      for (int ni = 0; ni < 4; ni++) {
        bf16x8 bkh = *(const bf16x8*)(&Ksh[swz(ni * 16 + fr, kf * 32 + kof)]);
        bf16x8 bkl = *(const bf16x8*)(&Ksl[swz(ni * 16 + fr, kf * 32 + kof)]);
        #pragma unroll
        for (int mi = 0; mi < 2; mi++) {
          sacc[mi][ni] = MFMA_BF16(aqh[mi][kf], bkh, sacc[mi][ni]);
          sacc[mi][ni] = MFMA_BF16(aql[mi][kf], bkh, sacc[mi][ni]);
          sacc[mi][ni] = MFMA_BF16(aqh[mi][kf], bkl, sacc[mi][ni]);
        }
      }
    }
    __builtin_amdgcn_s_setprio(0);

    // ---- online softmax with defer-max (THR=8, exp2 units) ----
    float tmr[2][4];
    bool need = false;
    #pragma unroll
    for (int mi = 0; mi < 2; mi++)
      #pragma unroll
      for (int r = 0; r < 4; r++) {
        float tm = fmaxf(fmaxf(sacc[mi][0][r], sacc[mi][1][r]),
                         fmaxf(sacc[mi][2][r], sacc[mi][3][r]));
        tm = fmaxf(tm, __shfl_xor(tm, 1));
        tm = fmaxf(tm, __shfl_xor(tm, 2));
        tm = fmaxf(tm, __shfl_xor(tm, 4));
        tm = fmaxf(tm, __shfl_xor(tm, 8));
        tmr[mi][r] = tm;
        need = need || (tm > mrun[mi][r] + 8.0f);
      }
    if (__ballot(need)) {
      #pragma unroll
      for (int mi = 0; mi < 2; mi++)
        #pragma unroll
        for (int r = 0; r < 4; r++) {
          float mn = fmaxf(mrun[mi][r], tmr[mi][r]);
          float s = exp2f(mrun[mi][r] - mn);
          mrun[mi][r] = mn;
          lrun[mi][r] *= s;
          #pragma unroll
          for (int ni = 0; ni < 4; ni++) oacc[mi][ni][r] *= s;
        }
    }
    #pragma unroll
    for (int mi = 0; mi < 2; mi++)
      #pragma unroll
      for (int r = 0; r < 4; r++)
        #pragma unroll
        for (int ni = 0; ni < 4; ni++)
          sacc[mi][ni][r] = exp2f(sacc[mi][ni][r] - mrun[mi][r]);

    VMW(0);            // V(t) landed
    RBAR(); SCHB();    // all waves finished QK^T -> K LDS free

    if (t + 1 < 16) issueK(t + 1);   // flies under P-store + PV

    // ---- P -> LDS (own wave region, 32 rows) ----
    bf16* Pwh = &Psh[w][0];
    bf16* Pwl = &Psl[w][0];
    #pragma unroll
    for (int mi = 0; mi < 2; mi++)
      #pragma unroll
      for (int ni = 0; ni < 4; ni++) {
        int col = ni * 16 + fr;
        #pragma unroll
        for (int r = 0; r < 4; r++) {
          int row = mi * 16 + ((lane >> 4) << 2) + r;
          unsigned short hi, lo;
          tsplit(sacc[mi][ni][r], hi, lo);
          Pwh[swz(row, col)] = hi;
          Pwl[swz(row, col)] = lo;
        }
      }

    // ---- PV (3-term) + row-sum via ones-MFMA ----
    f32x4 racc[2] = {zero, zero};
    __builtin_amdgcn_s_setprio(1);
    #pragma unroll
    for (int kf = 0; kf < 2; kf++) {
      bf16x8 pah[2], pal[2];
      #pragma unroll
      for (int mi = 0; mi < 2; mi++) {
        pah[mi] = *(const bf16x8*)(&Pwh[swz(mi * 16 + fr, kf * 32 + kof)]);
        pal[mi] = *(const bf16x8*)(&Pwl[swz(mi * 16 + fr, kf * 32 + kof)]);
      }
      #pragma unroll
      for (int ni = 0; ni < 4; ni++) {
        bf16x8 bvh = *(const bf16x8*)(&Vsh[swz(ni * 16 + fr, kf * 32 + kof)]);
        bf16x8 bvl = *(const bf16x8*)(&Vsl[swz(ni * 16 + fr, kf * 32 + kof)]);
        #pragma unroll
        for (int mi = 0; mi < 2; mi++) {
          oacc[mi][ni] = MFMA_BF16(pah[mi], bvh, oacc[mi][ni]);
          oacc[mi][ni] = MFMA_BF16(pal[mi], bvh, oacc[mi][ni]);
          oacc[mi][ni] = MFMA_BF16(pah[mi], bvl, oacc[mi][ni]);
        }
      }
      #pragma unroll
      for (int mi = 0; mi < 2; mi++) {
        racc[mi] = MFMA_BF16(pah[mi], vone, racc[mi]);
        racc[mi] = MFMA_BF16(pal[mi], vone, racc[mi]);
      }
    }
    __builtin_amdgcn_s_setprio(0);
    #pragma unroll
    for (int mi = 0; mi < 2; mi++)
      #pragma unroll
      for (int r = 0; r < 4; r++)
        lrun[mi][r] += racc[mi][r];

    RBAR();            // all waves done PV -> V LDS free
    if (t + 1 < 16) issueV(t + 1);   // flies under next QK^T + softmax
  }

  // store unnormalized partial O (fp32) + per-row (m, l)
  float* Pb = Pacc + (size_t)half * 8192 * 256;
  #pragma unroll
  for (int mi = 0; mi < 2; mi++)
    #pragma unroll
    for (int r = 0; r < 4; r++) {
      int nrow = n0 + w * 32 + mi * 16 + ((lane >> 4) << 2) + r;
      size_t row = xq + nrow;
      #pragma unroll
      for (int ni = 0; ni < 4; ni++)
        Pb[row * 256 + hd * 64 + ni * 16 + fr] = oacc[mi][ni][r];
      if (fr == 0) {
        float* mp = Ml + ((row * 4 + hd) << 2) + half * 2;
        mp[0] = mrun[mi][r];
        mp[1] = lrun[mi][r];
      }
    }
}

// ---------------------------------------------------------------------------
// Combine the two KV halves: O = (Pa*wa + Pb*wb) / (la*wa + lb*wb), hi/lo out.
// ---------------------------------------------------------------------------
__global__ __launch_bounds__(256) void attn_combine(
    const float* __restrict__ Pacc, const float* __restrict__ Ml,
    bf16* __restrict__ Oh, bf16* __restrict__ Ol)
{
  int tid = threadIdx.x, lane = tid & 63, w = tid >> 6;
  size_t row = (size_t)blockIdx.x * 4 + w;
  int hd = lane >> 4;
  int c0 = lane * 4;
  const float* mp = Ml + ((row * 4 + hd) << 2);
  float ma = mp[0], la = mp[1], mb = mp[2], lb = mp[3];
  float m = fmaxf(ma, mb);
  float wa = exp2f(ma - m), wb = exp2f(mb - m);
  float inv = 1.0f / (la * wa + lb * wb);
  wa *= inv; wb *= inv;
  f32x4 pa = *(const f32x4*)(Pacc + row * 256 + c0);
  f32x4 pb = *(const f32x4*)(Pacc + (size_t)8192 * 256 + row * 256 + c0);
  u16x4 vh, vl;
  #pragma unroll
  for (int r = 0; r < 4; r++) {
    unsigned short hi, lo;
    tsplit(pa[r] * wa + pb[r] * wb, hi, lo);
    vh[r] = hi; vl[r] = lo;
  }
  *(u16x4*)(Oh + row * 256 + c0) = vh;
  *(u16x4*)(Ol + row * 256 + c0) = vl;
}

// ---------------------------------------------------------------------------
extern "C" void kernel_launch(void* const* d_in, const int* in_sizes, int n_in,
                              void* d_out, int out_size, void* d_ws, size_t ws_size,
                              hipStream_t stream)
{
  (void)in_sizes; (void)n_in; (void)out_size; (void)ws_size;
  const float* desc0 = (const float*)d_in[0];
  const float* desc1 = (const float*)d_in[1];
  const float* Wq = (const float*)d_in[2];
  const float* bq = (const float*)d_in[3];
  const float* Wk = (const float*)d_in[4];
  const float* bk = (const float*)d_in[5];
  const float* Wv = (const float*)d_in[6];
  const float* bv = (const float*)d_in[7];
  const float* Wm = (const float*)d_in[8];
  const float* bm = (const float*)d_in[9];
  const float* W1 = (const float*)d_in[10];
  const float* b1 = (const float*)d_in[11];
  const float* gm = (const float*)d_in[12];
  const float* bt = (const float*)d_in[13];
  const float* W2 = (const float*)d_in[14];
  const float* b2 = (const float*)d_in[15];
  float* out = (float*)d_out;

  char* ws = (char*)d_ws;
  bf16*  Wbf  = (bf16*)(ws + 0);            //  31,457,280
  float* bias = (float*)(ws + 31457280);    //     110,592
  float* Dm   = (float*)(ws + 31567872);    //  16,777,216  fp32 master [xi,256]
  bf16*  Hin  = (bf16*)(ws + 48345088);     //  16,777,216  [xi,512] = xh | msg_h
  bf16*  XMl  = (bf16*)(ws + 65122304);     //  16,777,216  [xi,512] = xl | msg_l
  bf16*  Qh   = (bf16*)(ws + 81899520);     //   8,388,608
  bf16*  Ql   = (bf16*)(ws + 90288128);     //   8,388,608
  bf16*  Kh   = (bf16*)(ws + 98676736);     //   8,388,608
  bf16*  Kl   = (bf16*)(ws + 107065344);    //   8,388,608
  bf16*  Vth  = (bf16*)(ws + 115453952);    //   8,388,608  [db,256,2048]
  bf16*  Vtl  = (bf16*)(ws + 123842560);    //   8,388,608
  bf16*  Oh   = (bf16*)(ws + 132231168);    //   8,388,608
  bf16*  Ol   = (bf16*)(ws + 140619776);    //   8,388,608
  float* Pacc = (float*)(ws + 149008384);   //  16,777,216  [2][8192][256] fp32
  float* Ml   = (float*)(ws + 165785600);   //     524,288  [8192][4][4]
  // end: 166,309,888
  bf16*  Hbh  = Qh;                         // alias Qh+Ql (disjoint in time)
  bf16*  Hbl  = Kh;                         // alias Kh+Kl

  prep_weights<<<dim3(5130, 12), 256, 0, stream>>>(Wq, bq, Wk, bk, Wv, bv, Wm, bm,
                                                   W1, b1, gm, bt, W2, b2, Wbf, bias);
  transpose_in<<<dim3(64, 8, 4), dim3(32, 8), 0, stream>>>(desc0, desc1, Dm, Hin, XMl);

  for (int l = 0; l < NL; l++) {
    const bf16* wl = Wbf + (size_t)l * 1310720;
    const float* bl = bias + l * 2304;
    int cross = l & 1;
    // fused QKV (Q pre-scaled by log2e/8)
    gemm3<0, 128><<<dim3(64, 6), 256, 0, stream>>>(Hin, 512, XMl, 512,
        wl, wl + 196608, 256, bl, nullptr,
        Qh, Ql, Kh, Kl, Vth, Vtl, nullptr);
    // split-KV attention + combine
    attn3s<<<dim3(16, 16, 2), 256, 0, stream>>>(Qh, Ql, Kh, Kl, Vth, Vtl,
                                                Pacc, Ml, cross);
    attn_combine<<<2048, 256, 0, stream>>>(Pacc, Ml, Oh, Ol);
    // merge: msg = O·Wm^T
    gemm3<2, 64><<<dim3(64, 4), 256, 0, stream>>>(Oh, 256, Ol, 256,
        wl + 393216, wl + 458752, 256, bl + 768, nullptr,
        Hin, XMl, nullptr, nullptr, nullptr, nullptr, nullptr);
    // MLP1 + BN + ReLU
    gemm3<3, 128><<<dim3(64, 4), 256, 0, stream>>>(Hin, 512, XMl, 512,
        wl + 524288, wl + 786432, 512, bl + 1024, bl + 1536,
        Hbh, Hbl, nullptr, nullptr, nullptr, nullptr, nullptr);
    // MLP2 + residual
    gemm3<4, 64><<<dim3(64, 4), 256, 0, stream>>>(Hbh, 512, Hbl, 512,
        wl + 1048576, wl + 1179648, 512, bl + 2048, nullptr,
        Hin, XMl, nullptr, nullptr, nullptr, nullptr, Dm);
  }
  transpose_out<<<dim3(64, 8, 4), dim3(32, 8), 0, stream>>>(Dm, out);
}

// Round 11
// 2083.430 us; speedup vs baseline: 1.2400x; 1.2400x over previous
//
#include <hip/hip_runtime.h>

typedef unsigned short bf16;
typedef __attribute__((ext_vector_type(8))) short bf16x8;
typedef __attribute__((ext_vector_type(4))) float f32x4;
typedef unsigned short u16x4 __attribute__((ext_vector_type(4)));

#define DEVFN static __device__ __forceinline__

#define NL 12

#define VMW(N) asm volatile("s_waitcnt vmcnt(" #N ")" ::: "memory")
#define RBAR() asm volatile("s_barrier" ::: "memory")
#define SCHB() __builtin_amdgcn_sched_barrier(0)

DEVFN unsigned short f2bf(float f) {
  union { float f; unsigned u; } v; v.f = f;
  unsigned u = v.u;
  unsigned r = (u + 0x7fffu + ((u >> 16) & 1u)) >> 16;  // RNE
  return (unsigned short)r;
}
DEVFN float bf2f(unsigned short h) {
  union { unsigned u; float f; } v; v.u = ((unsigned)h) << 16; return v.f;
}
// truncation hi/lo split: 4 ALU ops, pair error ~2^-18
DEVFN void tsplit(float v, unsigned short& h, unsigned short& l) {
  union { float f; unsigned u; } a; a.f = v;
  h = (unsigned short)(a.u >> 16);
  union { float f; unsigned u; } b; b.u = a.u & 0xffff0000u;
  union { float f; unsigned u; } c; c.f = v - b.f;
  l = (unsigned short)(c.u >> 16);
}
// async global->LDS, 16B per lane; dest = wave-uniform base + lane*16
DEVFN void gll16(const bf16* g, bf16* l) {
  __builtin_amdgcn_global_load_lds(
      (const __attribute__((address_space(1))) unsigned int*)g,
      (__attribute__((address_space(3))) unsigned int*)l, 16, 0, 0);
}

#define MFMA_BF16(a, b, c) __builtin_amdgcn_mfma_f32_16x16x32_bf16((a), (b), (c), 0, 0, 0)

// ---------------------------------------------------------------------------
// Weight prep: hi/lo bf16 split of every weight (RNE, one-time). Wq/bq folded
// with Cs = log2(e)/8. Layout per layer (1310720 bf16):
//   [0,196608) Wqkv hi | [196608,393216) Wqkv lo | [393216,458752) Wm hi
//   [458752,524288) Wm lo | [524288,786432) W1 hi | [786432,1048576) W1 lo
//   [1048576,1179648) W2 hi | [1179648,1310720) W2 lo
// f32 bias block (2304): bqkv[768] | bm[256] | geff[512] | beff[512] | b2[256]
// ---------------------------------------------------------------------------
__global__ void prep_weights(const float* __restrict__ Wq, const float* __restrict__ bq,
                             const float* __restrict__ Wk, const float* __restrict__ bk,
                             const float* __restrict__ Wv, const float* __restrict__ bv,
                             const float* __restrict__ Wm, const float* __restrict__ bm,
                             const float* __restrict__ W1, const float* __restrict__ b1,
                             const float* __restrict__ gm, const float* __restrict__ bt,
                             const float* __restrict__ W2, const float* __restrict__ b2,
                             bf16* __restrict__ Wbf, float* __restrict__ bias)
{
  int l = blockIdx.y;
  bf16* wl = Wbf + (size_t)l * 1310720;
  float* bl = bias + l * 2304;
  int idx = blockIdx.x * blockDim.x + threadIdx.x;
  if (idx >= 1310720 + 2304) return;
  const float INV = 1.0f / sqrtf(1.0f + 1e-5f);
  const float Cs = 0.18033688011112042f;  // log2(e)/8

  float w = 0.f;
  int lo = 0;
  if (idx < 393216) {                         // Wqkv
    int j = idx; lo = (j >= 196608); j -= lo * 196608;
    int t = j >> 16;
    int p = (j >> 8) & 255;
    int k = j & 255;
    int c = ((p & 63) << 2) | (p >> 6);       // p = h*64+i -> c = i*4+h
    const float* W = (t == 0) ? Wq : (t == 1) ? Wk : Wv;
    w = W[(size_t)l * 65536 + c * 256 + k];
    if (t == 0) w *= Cs;
  } else if (idx < 524288) {                  // Wm (cols permuted)
    int j = idx - 393216; lo = (j >= 65536); j -= lo * 65536;
    int o = j >> 8, p = j & 255;
    int c = ((p & 63) << 2) | (p >> 6);
    w = Wm[(size_t)l * 65536 + o * 256 + c];
  } else if (idx < 1048576) {                 // W1
    int j = idx - 524288; lo = (j >= 262144); j &= 262143;
    w = W1[(size_t)l * 262144 + j];
  } else if (idx < 1310720) {                 // W2
    int j = idx - 1048576; lo = (j >= 131072); j &= 131071;
    w = W2[(size_t)l * 131072 + j];
  } else {
    int j = idx - 1310720;
    if (j < 768) {
      int t = j >> 8, p = j & 255;
      int c = ((p & 63) << 2) | (p >> 6);
      const float* bsrc = (t == 0) ? bq : (t == 1) ? bk : bv;
      bl[j] = bsrc[l * 256 + c] * ((t == 0) ? Cs : 1.0f);
    } else if (j < 1024) {
      bl[j] = bm[l * 256 + (j - 768)];
    } else if (j < 1536) {
      bl[j] = gm[l * 512 + (j - 1024)] * INV;
    } else if (j < 2048) {
      int o = j - 1536;
      bl[j] = gm[l * 512 + o] * INV * b1[l * 512 + o] + bt[l * 512 + o];
    } else {
      bl[j] = b2[l * 256 + (j - 2048)];
    }
    return;
  }
  unsigned short hi = f2bf(w);
  wl[idx] = lo ? f2bf(w - bf2f(hi)) : hi;
}

// ---------------------------------------------------------------------------
__global__ void transpose_in(const float* __restrict__ s0, const float* __restrict__ s1,
                             float* __restrict__ Dm, bf16* __restrict__ Hin,
                             bf16* __restrict__ XMl)
{
  __shared__ float t[32][33];
  int db = blockIdx.z;
  int dsc = db >> 1, bi = db & 1;
  const float* src = dsc ? s1 : s0;
  int n0 = blockIdx.x * 32, d0 = blockIdx.y * 32;
  int tx = threadIdx.x, ty = threadIdx.y;
  #pragma unroll
  for (int i = 0; i < 32; i += 8)
    t[ty + i][tx] = src[(size_t)(bi * 256 + d0 + ty + i) * 2048 + n0 + tx];
  __syncthreads();
  #pragma unroll
  for (int i = 0; i < 32; i += 8) {
    size_t xi = (size_t)db * 2048 + n0 + ty + i;
    float v = t[tx][ty + i];
    Dm[xi * 256 + d0 + tx] = v;
    unsigned short hi, lo;
    tsplit(v, hi, lo);
    Hin[xi * 512 + d0 + tx] = hi;
    XMl[xi * 512 + d0 + tx] = lo;
  }
}

__global__ void transpose_out(const float* __restrict__ Dm, float* __restrict__ out)
{
  __shared__ float t[32][33];
  int db = blockIdx.z;
  int n0 = blockIdx.x * 32, d0 = blockIdx.y * 32;
  int tx = threadIdx.x, ty = threadIdx.y;
  #pragma unroll
  for (int i = 0; i < 32; i += 8)
    t[ty + i][tx] = Dm[((size_t)db * 2048 + n0 + ty + i) * 256 + d0 + tx];
  __syncthreads();
  #pragma unroll
  for (int i = 0; i < 32; i += 8)
    out[(size_t)(db * 256 + d0 + ty + i) * 2048 + n0 + tx] = t[tx][ty + i];
}

// ---------------------------------------------------------------------------
// 3-term split GEMM, tile 128xNT (NT=128 QKV/MLP1, NT=64 merge/MLP2), BK=32,
// 4 waves (2x2). Double-buffered global_load_lds, counted vmcnt + raw bars.
// Granule-major LDS slots (conflict-free, validated r9/r10): read addr
// (row>>4)*512 + g*128 + (row&15)*8; staging source lane -> (row=lane&15,
// granule=lane>>4).
// ---------------------------------------------------------------------------
DEVFN int gidx(int row, int g) { return ((row >> 4) << 9) + (g << 7) + ((row & 15) << 3); }

template<int EPI, int NT>
__global__ __launch_bounds__(256, (NT == 128) ? 2 : 3) void gemm3(
    const bf16* __restrict__ Ah, int lda,
    const bf16* __restrict__ Al, int ldal,
    const bf16* __restrict__ Wh, const bf16* __restrict__ Wl, int K,
    const float* __restrict__ b0, const float* __restrict__ b1,
    bf16* __restrict__ o0, bf16* __restrict__ o1,
    bf16* __restrict__ o2, bf16* __restrict__ o3,
    bf16* __restrict__ o4, bf16* __restrict__ o5,
    float* __restrict__ of)
{
  constexpr int NFR = NT / 32;
  __shared__ bf16 AsH[2][4096];
  __shared__ bf16 AsL[2][4096];
  __shared__ bf16 BsH[2][NT * 32];
  __shared__ bf16 BsL[2][NT * 32];
  int tid = threadIdx.x, lane = tid & 63, wid = tid >> 6;
  int wr = wid >> 1, wc = wid & 1;
  int m0 = blockIdx.x * 128, n0 = blockIdx.y * NT;

  // granule-major staging source
  int srow = lane & 15, sg = (lane >> 4) << 3;
  const bf16* A0h = Ah + (size_t)(m0 + wid * 16 + srow) * lda + sg;
  const bf16* A0l = Al + (size_t)(m0 + wid * 16 + srow) * ldal + sg;
  const bf16* B0h = Wh + (size_t)(n0 + wid * 16 + srow) * K + sg;
  const bf16* B0l = Wl + (size_t)(n0 + wid * 16 + srow) * K + sg;
  size_t a64h = (size_t)64 * lda, a64l = (size_t)64 * ldal, b64 = (size_t)64 * K;

  auto issue = [&](int k0, int b) {
    gll16(A0h + k0, &AsH[b][wid * 512]);
    gll16(A0h + a64h + k0, &AsH[b][2048 + wid * 512]);
    gll16(A0l + k0, &AsL[b][wid * 512]);
    gll16(A0l + a64l + k0, &AsL[b][2048 + wid * 512]);
    gll16(B0h + k0, &BsH[b][wid * 512]);
    gll16(B0l + k0, &BsL[b][wid * 512]);
    if constexpr (NT == 128) {
      gll16(B0h + b64 + k0, &BsH[b][2048 + wid * 512]);
      gll16(B0l + b64 + k0, &BsL[b][2048 + wid * 512]);
    }
  };

  f32x4 zero = {0.f, 0.f, 0.f, 0.f};
  f32x4 acc[4][NFR];
  #pragma unroll
  for (int i = 0; i < 4; i++)
    #pragma unroll
    for (int j = 0; j < NFR; j++) acc[i][j] = zero;

  int fr = lane & 15, g = lane >> 4;
  int cb = wc * (NT / 2);
  int nk = K >> 5;

  issue(0, 0);
  for (int ks = 0; ks < nk; ks++) {
    int cur = ks & 1;
    if (ks + 1 < nk) {
      issue((ks + 1) << 5, cur ^ 1);
      if constexpr (NT == 128) VMW(8); else VMW(6);
    } else {
      VMW(0);
    }
    RBAR(); SCHB();
    bf16x8 afh[4], afl[4], bfh[NFR], bfl[NFR];
    #pragma unroll
    for (int i = 0; i < 4; i++) {
      afh[i] = *(const bf16x8*)(&AsH[cur][gidx(wr * 64 + i * 16 + fr, g)]);
      afl[i] = *(const bf16x8*)(&AsL[cur][gidx(wr * 64 + i * 16 + fr, g)]);
    }
    #pragma unroll
    for (int i = 0; i < NFR; i++) {
      bfh[i] = *(const bf16x8*)(&BsH[cur][gidx(cb + i * 16 + fr, g)]);
      bfl[i] = *(const bf16x8*)(&BsL[cur][gidx(cb + i * 16 + fr, g)]);
    }
    #pragma unroll
    for (int mi = 0; mi < 4; mi++)
      #pragma unroll
      for (int ni = 0; ni < NFR; ni++) {
        acc[mi][ni] = MFMA_BF16(afh[mi], bfh[ni], acc[mi][ni]);
        acc[mi][ni] = MFMA_BF16(afl[mi], bfh[ni], acc[mi][ni]);
        acc[mi][ni] = MFMA_BF16(afh[mi], bfl[ni], acc[mi][ni]);
      }
    RBAR();
  }

  #pragma unroll
  for (int mi = 0; mi < 4; mi++) {
    #pragma unroll
    for (int ni = 0; ni < NFR; ni++) {
      int mrow = m0 + wr * 64 + mi * 16 + ((lane >> 4) << 2);
      int ocol = n0 + cb + ni * 16 + fr;
      if constexpr (EPI == 0) {          // fused QKV
        float bb = b0[ocol];
        if (ocol < 512) {
          bf16* Dh = (ocol < 256) ? o0 : o2;
          bf16* Dl = (ocol < 256) ? o1 : o3;
          int oo = ocol & 255;
          #pragma unroll
          for (int r = 0; r < 4; r++) {
            unsigned short hi, lo;
            tsplit(acc[mi][ni][r] + bb, hi, lo);
            Dh[(size_t)(mrow + r) * 256 + oo] = hi;
            Dl[(size_t)(mrow + r) * 256 + oo] = lo;
          }
        } else {
          int c = ocol - 512;
          int dbi = mrow >> 11, nn = mrow & 2047;
          u16x4 ph, pl;
          #pragma unroll
          for (int r = 0; r < 4; r++) {
            unsigned short hi, lo;
            tsplit(acc[mi][ni][r] + bb, hi, lo);
            ph[r] = hi; pl[r] = lo;
          }
          *(u16x4*)(&o4[((size_t)dbi * 256 + c) * 2048 + nn]) = ph;
          *(u16x4*)(&o5[((size_t)dbi * 256 + c) * 2048 + nn]) = pl;
        }
      } else if constexpr (EPI == 2) {   // merge -> msg hi+lo
        float bb = b0[ocol];
        #pragma unroll
        for (int r = 0; r < 4; r++) {
          unsigned short hi, lo;
          tsplit(acc[mi][ni][r] + bb, hi, lo);
          o0[(size_t)(mrow + r) * 512 + 256 + ocol] = hi;
          o1[(size_t)(mrow + r) * 512 + 256 + ocol] = lo;
        }
      } else if constexpr (EPI == 3) {   // BN+ReLU hi+lo
        float ge = b0[ocol], be = b1[ocol];
        #pragma unroll
        for (int r = 0; r < 4; r++) {
          unsigned short hi, lo;
          tsplit(fmaxf(ge * acc[mi][ni][r] + be, 0.f), hi, lo);
          o0[(size_t)(mrow + r) * 512 + ocol] = hi;
          o1[(size_t)(mrow + r) * 512 + ocol] = lo;
        }
      } else {                           // EPI 4: residual
        float bb = b0[ocol];
        #pragma unroll
        for (int r = 0; r < 4; r++) {
          size_t ix = (size_t)(mrow + r) * 256 + ocol;
          float d = of[ix] + acc[mi][ni][r] + bb;
          of[ix] = d;
          unsigned short hi, lo;
          tsplit(d, hi, lo);
          o0[(size_t)(mrow + r) * 512 + ocol] = hi;
          o1[(size_t)(mrow + r) * 512 + ocol] = lo;
        }
      }
    }
  }
}

// ---------------------------------------------------------------------------
// Flash attention (round-8 structure, the best measured): split-KV (2 halves),
// 8 waves x 16 rows, 3-term QK^T/PV, 3-phase pipelined, defer-max.
// ---------------------------------------------------------------------------
DEVFN int swz(int row, int col) { return row * 64 + (col ^ ((row & 7) << 3)); }

__global__ __launch_bounds__(512, 4) void attn3s(
    const bf16* __restrict__ Qh, const bf16* __restrict__ Ql,
    const bf16* __restrict__ Kh, const bf16* __restrict__ Kl,
    const bf16* __restrict__ Vth, const bf16* __restrict__ Vtl,
    float* __restrict__ Pacc, float* __restrict__ Ml, int cross)
{
  __shared__ bf16 Ksh[64 * 64];
  __shared__ bf16 Ksl[64 * 64];
  __shared__ bf16 Vsh[64 * 64];
  __shared__ bf16 Vsl[64 * 64];
  __shared__ bf16 Psh[8][1024];
  __shared__ bf16 Psl[8][1024];
  int tid = threadIdx.x, lane = tid & 63, w = tid >> 6;
  int inst = blockIdx.y;
  int half = blockIdx.z;
  int db = inst >> 2, hd = inst & 3;
  int dsc = db >> 1, bi = db & 1;
  int sdb = (cross ? (1 - dsc) : dsc) * 2 + bi;
  size_t xq = (size_t)db * 2048;
  size_t xs = (size_t)sdb * 2048 + half * 1024;
  int n0 = blockIdx.x * 128;

  int fr = lane & 15, kof = (lane >> 4) << 3;

  // Q fragments hi/lo: direct global -> registers
  bf16x8 aqh[2], aql[2];
  #pragma unroll
  for (int kf = 0; kf < 2; kf++) {
    size_t g = (xq + n0 + w * 16 + fr) * 256 + hd * 64 + kf * 32 + kof;
    aqh[kf] = *(const bf16x8*)(Qh + g);
    aql[kf] = *(const bf16x8*)(Ql + g);
  }

  f32x4 zero = {0.f, 0.f, 0.f, 0.f};
  f32x4 oacc[4];
  #pragma unroll
  for (int ni = 0; ni < 4; ni++) oacc[ni] = zero;
  float mrun[4], lrun[4];
  #pragma unroll
  for (int r = 0; r < 4; r++) { mrun[r] = -3.0e38f; lrun[r] = 0.f; }

  bf16x8 vone;
  #pragma unroll
  for (int i = 0; i < 8; i++) vone[i] = (short)0x3F80;  // bf16 1.0

  // staging sources (pre-swizzled): lane -> row w*8 + (lane>>3),
  // granule (lane&7) ^ (row&7)
  int lrow = lane >> 3;
  int g8 = ((lane & 7) ^ (lrow & 7)) << 3;
  int krow = w * 8 + lrow;
  const bf16* Ksrc_h = Kh + (xs + krow) * 256 + hd * 64 + g8;
  const bf16* Ksrc_l = Kl + (xs + krow) * 256 + hd * 64 + g8;
  const bf16* Vsrc_h = Vth + ((size_t)sdb * 256 + hd * 64 + krow) * 2048 + half * 1024 + g8;
  const bf16* Vsrc_l = Vtl + ((size_t)sdb * 256 + hd * 64 + krow) * 2048 + half * 1024 + g8;
  bf16* LKh = Ksh + w * 512;
  bf16* LKl = Ksl + w * 512;
  bf16* LVh = Vsh + w * 512;
  bf16* LVl = Vsl + w * 512;

  // prologue: K(0) then V(0) in flight
  gll16(Ksrc_h, LKh);
  gll16(Ksrc_l, LKl);
  gll16(Vsrc_h, LVh);
  gll16(Vsrc_l, LVl);

  for (int t = 0; t < 16; t++) {
    VMW(2);            // K(t) landed (V(t) may still be in flight)
    RBAR(); SCHB();

    // ---- QK^T (3-term) ----
    f32x4 sacc[4];
    #pragma unroll
    for (int ni = 0; ni < 4; ni++) sacc[ni] = zero;
    #pragma unroll
    for (int kf = 0; kf < 2; kf++) {
      #pragma unroll
      for (int ni = 0; ni < 4; ni++) {
        bf16x8 bkh = *(const bf16x8*)(&Ksh[swz(ni * 16 + fr, kf * 32 + kof)]);
        bf16x8 bkl = *(const bf16x8*)(&Ksl[swz(ni * 16 + fr, kf * 32 + kof)]);
        sacc[ni] = MFMA_BF16(aqh[kf], bkh, sacc[ni]);
        sacc[ni] = MFMA_BF16(aql[kf], bkh, sacc[ni]);
        sacc[ni] = MFMA_BF16(aqh[kf], bkl, sacc[ni]);
      }
    }

    // ---- online softmax with defer-max (T13, exp2 units, THR=8) ----
    float tmr[4];
    bool need = false;
    #pragma unroll
    for (int r = 0; r < 4; r++) {
      float tm = fmaxf(fmaxf(sacc[0][r], sacc[1][r]), fmaxf(sacc[2][r], sacc[3][r]));
      tm = fmaxf(tm, __shfl_xor(tm, 1));
      tm = fmaxf(tm, __shfl_xor(tm, 2));
      tm = fmaxf(tm, __shfl_xor(tm, 4));
      tm = fmaxf(tm, __shfl_xor(tm, 8));
      tmr[r] = tm;
      need = need || (tm > mrun[r] + 8.0f);
    }
    if (__ballot(need)) {
      #pragma unroll
      for (int r = 0; r < 4; r++) {
        float mn = fmaxf(mrun[r], tmr[r]);
        float s = exp2f(mrun[r] - mn);
        mrun[r] = mn;
        lrun[r] *= s;
        #pragma unroll
        for (int ni = 0; ni < 4; ni++) oacc[ni][r] *= s;
      }
    }
    #pragma unroll
    for (int r = 0; r < 4; r++)
      #pragma unroll
      for (int ni = 0; ni < 4; ni++)
        sacc[ni][r] = exp2f(sacc[ni][r] - mrun[r]);

    VMW(0);            // V(t) landed (K(t+1) not yet issued)
    RBAR(); SCHB();    // also: all waves finished QK^T -> K LDS free

    if (t + 1 < 16) {  // K(t+1) flies under P-store + PV
      gll16(Ksrc_h + (size_t)(t + 1) * 16384, LKh);
      gll16(Ksrc_l + (size_t)(t + 1) * 16384, LKl);
    }

    // ---- P -> LDS (own wave region) ----
    bf16* Pwh = &Psh[w][0];
    bf16* Pwl = &Psl[w][0];
    #pragma unroll
    for (int ni = 0; ni < 4; ni++) {
      int col = ni * 16 + fr;
      #pragma unroll
      for (int r = 0; r < 4; r++) {
        int row = ((lane >> 4) << 2) + r;
        unsigned short hi, lo;
        tsplit(sacc[ni][r], hi, lo);
        Pwh[swz(row, col)] = hi;
        Pwl[swz(row, col)] = lo;
      }
    }

    // ---- PV (3-term) + row-sum via ones-MFMA ----
    f32x4 racc = zero;
    #pragma unroll
    for (int kf = 0; kf < 2; kf++) {
      bf16x8 pah = *(const bf16x8*)(&Pwh[swz(fr, kf * 32 + kof)]);
      bf16x8 pal = *(const bf16x8*)(&Pwl[swz(fr, kf * 32 + kof)]);
      #pragma unroll
      for (int ni = 0; ni < 4; ni++) {
        bf16x8 bvh = *(const bf16x8*)(&Vsh[swz(ni * 16 + fr, kf * 32 + kof)]);
        bf16x8 bvl = *(const bf16x8*)(&Vsl[swz(ni * 16 + fr, kf * 32 + kof)]);
        oacc[ni] = MFMA_BF16(pah, bvh, oacc[ni]);
        oacc[ni] = MFMA_BF16(pal, bvh, oacc[ni]);
        oacc[ni] = MFMA_BF16(pah, bvl, oacc[ni]);
      }
      racc = MFMA_BF16(pah, vone, racc);
      racc = MFMA_BF16(pal, vone, racc);
    }
    #pragma unroll
    for (int r = 0; r < 4; r++)
      lrun[r] += racc[r];

    RBAR();            // all waves done PV -> V LDS free
    if (t + 1 < 16) {  // V(t+1) flies under next QK^T + softmax
      gll16(Vsrc_h + (t + 1) * 64, LVh);
      gll16(Vsrc_l + (t + 1) * 64, LVl);
    }
  }

  // store unnormalized partial O (fp32) + per-row (m, l)
  float* Pb = Pacc + (size_t)half * 8192 * 256;
  #pragma unroll
  for (int r = 0; r < 4; r++) {
    int nrow = n0 + w * 16 + ((lane >> 4) << 2) + r;
    size_t row = xq + nrow;
    #pragma unroll
    for (int ni = 0; ni < 4; ni++)
      Pb[row * 256 + hd * 64 + ni * 16 + fr] = oacc[ni][r];
    if (fr == 0) {
      float* mp = Ml + ((row * 4 + hd) << 2) + half * 2;
      mp[0] = mrun[r];
      mp[1] = lrun[r];
    }
  }
}

// ---------------------------------------------------------------------------
// Combine the two KV halves: O = (Pa*wa + Pb*wb) / (la*wa + lb*wb), hi/lo out.
// ---------------------------------------------------------------------------
__global__ __launch_bounds__(256) void attn_combine(
    const float* __restrict__ Pacc, const float* __restrict__ Ml,
    bf16* __restrict__ Oh, bf16* __restrict__ Ol)
{
  int tid = threadIdx.x, lane = tid & 63, w = tid >> 6;
  size_t row = (size_t)blockIdx.x * 4 + w;
  int hd = lane >> 4;
  int c0 = lane * 4;
  const float* mp = Ml + ((row * 4 + hd) << 2);
  float ma = mp[0], la = mp[1], mb = mp[2], lb = mp[3];
  float m = fmaxf(ma, mb);
  float wa = exp2f(ma - m), wb = exp2f(mb - m);
  float inv = 1.0f / (la * wa + lb * wb);
  wa *= inv; wb *= inv;
  f32x4 pa = *(const f32x4*)(Pacc + row * 256 + c0);
  f32x4 pb = *(const f32x4*)(Pacc + (size_t)8192 * 256 + row * 256 + c0);
  u16x4 vh, vl;
  #pragma unroll
  for (int r = 0; r < 4; r++) {
    unsigned short hi, lo;
    tsplit(pa[r] * wa + pb[r] * wb, hi, lo);
    vh[r] = hi; vl[r] = lo;
  }
  *(u16x4*)(Oh + row * 256 + c0) = vh;
  *(u16x4*)(Ol + row * 256 + c0) = vl;
}

// ---------------------------------------------------------------------------
extern "C" void kernel_launch(void* const* d_in, const int* in_sizes, int n_in,
                              void* d_out, int out_size, void* d_ws, size_t ws_size,
                              hipStream_t stream)
{
  (void)in_sizes; (void)n_in; (void)out_size; (void)ws_size;
  const float* desc0 = (const float*)d_in[0];
  const float* desc1 = (const float*)d_in[1];
  const float* Wq = (const float*)d_in[2];
  const float* bq = (const float*)d_in[3];
  const float* Wk = (const float*)d_in[4];
  const float* bk = (const float*)d_in[5];
  const float* Wv = (const float*)d_in[6];
  const float* bv = (const float*)d_in[7];
  const float* Wm = (const float*)d_in[8];
  const float* bm = (const float*)d_in[9];
  const float* W1 = (const float*)d_in[10];
  const float* b1 = (const float*)d_in[11];
  const float* gm = (const float*)d_in[12];
  const float* bt = (const float*)d_in[13];
  const float* W2 = (const float*)d_in[14];
  const float* b2 = (const float*)d_in[15];
  float* out = (float*)d_out;

  char* ws = (char*)d_ws;
  bf16*  Wbf  = (bf16*)(ws + 0);            //  31,457,280
  float* bias = (float*)(ws + 31457280);    //     110,592
  float* Dm   = (float*)(ws + 31567872);    //  16,777,216  fp32 master [xi,256]
  bf16*  Hin  = (bf16*)(ws + 48345088);     //  16,777,216  [xi,512] = xh | msg_h
  bf16*  XMl  = (bf16*)(ws + 65122304);     //  16,777,216  [xi,512] = xl | msg_l
  bf16*  Qh   = (bf16*)(ws + 81899520);     //   8,388,608
  bf16*  Ql   = (bf16*)(ws + 90288128);     //   8,388,608
  bf16*  Kh   = (bf16*)(ws + 98676736);     //   8,388,608
  bf16*  Kl   = (bf16*)(ws + 107065344);    //   8,388,608
  bf16*  Vth  = (bf16*)(ws + 115453952);    //   8,388,608  [db,256,2048]
  bf16*  Vtl  = (bf16*)(ws + 123842560);    //   8,388,608
  bf16*  Oh   = (bf16*)(ws + 132231168);    //   8,388,608
  bf16*  Ol   = (bf16*)(ws + 140619776);    //   8,388,608
  float* Pacc = (float*)(ws + 149008384);   //  16,777,216  [2][8192][256] fp32
  float* Ml   = (float*)(ws + 165785600);   //     524,288  [8192][4][4]
  // end: 166,309,888
  bf16*  Hbh  = Qh;                         // alias Qh+Ql (disjoint in time)
  bf16*  Hbl  = Kh;                         // alias Kh+Kl

  prep_weights<<<dim3(5130, 12), 256, 0, stream>>>(Wq, bq, Wk, bk, Wv, bv, Wm, bm,
                                                   W1, b1, gm, bt, W2, b2, Wbf, bias);
  transpose_in<<<dim3(64, 8, 4), dim3(32, 8), 0, stream>>>(desc0, desc1, Dm, Hin, XMl);

  for (int l = 0; l < NL; l++) {
    const bf16* wl = Wbf + (size_t)l * 1310720;
    const float* bl = bias + l * 2304;
    int cross = l & 1;
    // fused QKV (Q pre-scaled by log2e/8)
    gemm3<0, 128><<<dim3(64, 6), 256, 0, stream>>>(Hin, 512, XMl, 512,
        wl, wl + 196608, 256, bl, nullptr,
        Qh, Ql, Kh, Kl, Vth, Vtl, nullptr);
    // split-KV attention + combine
    attn3s<<<dim3(16, 16, 2), 512, 0, stream>>>(Qh, Ql, Kh, Kl, Vth, Vtl,
                                                Pacc, Ml, cross);
    attn_combine<<<2048, 256, 0, stream>>>(Pacc, Ml, Oh, Ol);
    // merge: msg = O·Wm^T
    gemm3<2, 64><<<dim3(64, 4), 256, 0, stream>>>(Oh, 256, Ol, 256,
        wl + 393216, wl + 458752, 256, bl + 768, nullptr,
        Hin, XMl, nullptr, nullptr, nullptr, nullptr, nullptr);
    // MLP1 + BN + ReLU
    gemm3<3, 128><<<dim3(64, 4), 256, 0, stream>>>(Hin, 512, XMl, 512,
        wl + 524288, wl + 786432, 512, bl + 1024, bl + 1536,
        Hbh, Hbl, nullptr, nullptr, nullptr, nullptr, nullptr);
    // MLP2 + residual
    gemm3<4, 64><<<dim3(64, 4), 256, 0, stream>>>(Hbh, 512, Hbl, 512,
        wl + 1048576, wl + 1179648, 512, bl + 2048, nullptr,
        Hin, XMl, nullptr, nullptr, nullptr, nullptr, Dm);
  }
  transpose_out<<<dim3(64, 8, 4), dim3(32, 8), 0, stream>>>(Dm, out);
}

// Round 12
// 1870.672 us; speedup vs baseline: 1.3810x; 1.1137x over previous
//
#include <hip/hip_runtime.h>

typedef unsigned short bf16;
typedef __attribute__((ext_vector_type(8))) short bf16x8;
typedef __attribute__((ext_vector_type(4))) float f32x4;
typedef unsigned short u16x4 __attribute__((ext_vector_type(4)));

#define DEVFN static __device__ __forceinline__

#define NL 12

#define VMW(N) asm volatile("s_waitcnt vmcnt(" #N ")" ::: "memory")
#define RBAR() asm volatile("s_barrier" ::: "memory")
#define SCHB() __builtin_amdgcn_sched_barrier(0)

DEVFN unsigned short f2bf(float f) {
  union { float f; unsigned u; } v; v.f = f;
  unsigned u = v.u;
  unsigned r = (u + 0x7fffu + ((u >> 16) & 1u)) >> 16;  // RNE
  return (unsigned short)r;
}
DEVFN float bf2f(unsigned short h) {
  union { unsigned u; float f; } v; v.u = ((unsigned)h) << 16; return v.f;
}
// truncation hi/lo split: 4 ALU ops, pair error ~2^-18
DEVFN void tsplit(float v, unsigned short& h, unsigned short& l) {
  union { float f; unsigned u; } a; a.f = v;
  h = (unsigned short)(a.u >> 16);
  union { float f; unsigned u; } b; b.u = a.u & 0xffff0000u;
  union { float f; unsigned u; } c; c.f = v - b.f;
  l = (unsigned short)(c.u >> 16);
}
// async global->LDS, 16B per lane; dest = wave-uniform base + lane*16
DEVFN void gll16(const bf16* g, bf16* l) {
  __builtin_amdgcn_global_load_lds(
      (const __attribute__((address_space(1))) unsigned int*)g,
      (__attribute__((address_space(3))) unsigned int*)l, 16, 0, 0);
}

#define MFMA_BF16(a, b, c) __builtin_amdgcn_mfma_f32_16x16x32_bf16((a), (b), (c), 0, 0, 0)

// ---------------------------------------------------------------------------
// Weight prep: hi/lo bf16 split of every weight (RNE, one-time). Wq/bq folded
// with Cs = log2(e)/8. Layout per layer (1310720 bf16):
//   [0,196608) Wqkv hi | [196608,393216) Wqkv lo | [393216,458752) Wm hi
//   [458752,524288) Wm lo | [524288,786432) W1 hi | [786432,1048576) W1 lo
//   [1048576,1179648) W2 hi | [1179648,1310720) W2 lo
// f32 bias block (2304): bqkv[768] | bm[256] | geff[512] | beff[512] | b2[256]
// ---------------------------------------------------------------------------
__global__ void prep_weights(const float* __restrict__ Wq, const float* __restrict__ bq,
                             const float* __restrict__ Wk, const float* __restrict__ bk,
                             const float* __restrict__ Wv, const float* __restrict__ bv,
                             const float* __restrict__ Wm, const float* __restrict__ bm,
                             const float* __restrict__ W1, const float* __restrict__ b1,
                             const float* __restrict__ gm, const float* __restrict__ bt,
                             const float* __restrict__ W2, const float* __restrict__ b2,
                             bf16* __restrict__ Wbf, float* __restrict__ bias)
{
  int l = blockIdx.y;
  bf16* wl = Wbf + (size_t)l * 1310720;
  float* bl = bias + l * 2304;
  int idx = blockIdx.x * blockDim.x + threadIdx.x;
  if (idx >= 1310720 + 2304) return;
  const float INV = 1.0f / sqrtf(1.0f + 1e-5f);
  const float Cs = 0.18033688011112042f;  // log2(e)/8

  float w = 0.f;
  int lo = 0;
  if (idx < 393216) {                         // Wqkv
    int j = idx; lo = (j >= 196608); j -= lo * 196608;
    int t = j >> 16;
    int p = (j >> 8) & 255;
    int k = j & 255;
    int c = ((p & 63) << 2) | (p >> 6);       // p = h*64+i -> c = i*4+h
    const float* W = (t == 0) ? Wq : (t == 1) ? Wk : Wv;
    w = W[(size_t)l * 65536 + c * 256 + k];
    if (t == 0) w *= Cs;
  } else if (idx < 524288) {                  // Wm (cols permuted)
    int j = idx - 393216; lo = (j >= 65536); j -= lo * 65536;
    int o = j >> 8, p = j & 255;
    int c = ((p & 63) << 2) | (p >> 6);
    w = Wm[(size_t)l * 65536 + o * 256 + c];
  } else if (idx < 1048576) {                 // W1
    int j = idx - 524288; lo = (j >= 262144); j &= 262143;
    w = W1[(size_t)l * 262144 + j];
  } else if (idx < 1310720) {                 // W2
    int j = idx - 1048576; lo = (j >= 131072); j &= 131071;
    w = W2[(size_t)l * 131072 + j];
  } else {
    int j = idx - 1310720;
    if (j < 768) {
      int t = j >> 8, p = j & 255;
      int c = ((p & 63) << 2) | (p >> 6);
      const float* bsrc = (t == 0) ? bq : (t == 1) ? bk : bv;
      bl[j] = bsrc[l * 256 + c] * ((t == 0) ? Cs : 1.0f);
    } else if (j < 1024) {
      bl[j] = bm[l * 256 + (j - 768)];
    } else if (j < 1536) {
      bl[j] = gm[l * 512 + (j - 1024)] * INV;
    } else if (j < 2048) {
      int o = j - 1536;
      bl[j] = gm[l * 512 + o] * INV * b1[l * 512 + o] + bt[l * 512 + o];
    } else {
      bl[j] = b2[l * 256 + (j - 2048)];
    }
    return;
  }
  unsigned short hi = f2bf(w);
  wl[idx] = lo ? f2bf(w - bf2f(hi)) : hi;
}

// ---------------------------------------------------------------------------
__global__ void transpose_in(const float* __restrict__ s0, const float* __restrict__ s1,
                             float* __restrict__ Dm, bf16* __restrict__ Hin,
                             bf16* __restrict__ XMl)
{
  __shared__ float t[32][33];
  int db = blockIdx.z;
  int dsc = db >> 1, bi = db & 1;
  const float* src = dsc ? s1 : s0;
  int n0 = blockIdx.x * 32, d0 = blockIdx.y * 32;
  int tx = threadIdx.x, ty = threadIdx.y;
  #pragma unroll
  for (int i = 0; i < 32; i += 8)
    t[ty + i][tx] = src[(size_t)(bi * 256 + d0 + ty + i) * 2048 + n0 + tx];
  __syncthreads();
  #pragma unroll
  for (int i = 0; i < 32; i += 8) {
    size_t xi = (size_t)db * 2048 + n0 + ty + i;
    float v = t[tx][ty + i];
    Dm[xi * 256 + d0 + tx] = v;
    unsigned short hi, lo;
    tsplit(v, hi, lo);
    Hin[xi * 512 + d0 + tx] = hi;
    XMl[xi * 512 + d0 + tx] = lo;
  }
}

__global__ void transpose_out(const float* __restrict__ Dm, float* __restrict__ out)
{
  __shared__ float t[32][33];
  int db = blockIdx.z;
  int n0 = blockIdx.x * 32, d0 = blockIdx.y * 32;
  int tx = threadIdx.x, ty = threadIdx.y;
  #pragma unroll
  for (int i = 0; i < 32; i += 8)
    t[ty + i][tx] = Dm[((size_t)db * 2048 + n0 + ty + i) * 256 + d0 + tx];
  __syncthreads();
  #pragma unroll
  for (int i = 0; i < 32; i += 8)
    out[(size_t)(db * 256 + d0 + ty + i) * 2048 + n0 + tx] = t[tx][ty + i];
}

// ---------------------------------------------------------------------------
// 3-term split GEMM, tile 128xNT (NT=128 QKV/MLP1, NT=64 merge/MLP2), BK=32,
// 4 waves (2x2). Double-buffered global_load_lds, counted vmcnt + raw bars.
// sigma-swizzle, sigma(row) = (row>>1)&3:
//   - staging source: lane -> row wid*16+(lane>>2), granule (lane&3)^sigma
//     => each quad reads 64B contiguous (coalesced, like r8);
//   - read banks: 16*fr + 4*((fr>>1)&3) => 8 bank-quads x 2-way (free, unlike r8).
// ---------------------------------------------------------------------------
DEVFN int gsw2(int row, int g) { return row * 32 + (((g ^ (row >> 1)) & 3) << 3); }

template<int EPI, int NT>
__global__ __launch_bounds__(256, (NT == 128) ? 2 : 3) void gemm3(
    const bf16* __restrict__ Ah, int lda,
    const bf16* __restrict__ Al, int ldal,
    const bf16* __restrict__ Wh, const bf16* __restrict__ Wl, int K,
    const float* __restrict__ b0, const float* __restrict__ b1,
    bf16* __restrict__ o0, bf16* __restrict__ o1,
    bf16* __restrict__ o2, bf16* __restrict__ o3,
    bf16* __restrict__ o4, bf16* __restrict__ o5,
    float* __restrict__ of)
{
  constexpr int NFR = NT / 32;
  __shared__ bf16 AsH[2][4096];
  __shared__ bf16 AsL[2][4096];
  __shared__ bf16 BsH[2][NT * 32];
  __shared__ bf16 BsL[2][NT * 32];
  int tid = threadIdx.x, lane = tid & 63, wid = tid >> 6;
  int wr = wid >> 1, wc = wid & 1;
  int m0 = blockIdx.x * 128, n0 = blockIdx.y * NT;

  // staging source: row = wid*16 + (lane>>2); granule p=(lane&3)^sigma(row),
  // sigma(row) = (row>>1)&3 = (lane>>3)&3 (wid*16 contributes 0 mod 4)
  int lrow = lane >> 2;
  int g4 = (((lane & 3) ^ (lane >> 3)) & 3) << 3;
  const bf16* A0h = Ah + (size_t)(m0 + wid * 16 + lrow) * lda + g4;
  const bf16* A0l = Al + (size_t)(m0 + wid * 16 + lrow) * ldal + g4;
  const bf16* B0h = Wh + (size_t)(n0 + wid * 16 + lrow) * K + g4;
  const bf16* B0l = Wl + (size_t)(n0 + wid * 16 + lrow) * K + g4;
  size_t a64h = (size_t)64 * lda, a64l = (size_t)64 * ldal, b64 = (size_t)64 * K;

  auto issue = [&](int k0, int b) {
    gll16(A0h + k0, &AsH[b][wid * 512]);
    gll16(A0h + a64h + k0, &AsH[b][2048 + wid * 512]);
    gll16(A0l + k0, &AsL[b][wid * 512]);
    gll16(A0l + a64l + k0, &AsL[b][2048 + wid * 512]);
    gll16(B0h + k0, &BsH[b][wid * 512]);
    gll16(B0l + k0, &BsL[b][wid * 512]);
    if constexpr (NT == 128) {
      gll16(B0h + b64 + k0, &BsH[b][2048 + wid * 512]);
      gll16(B0l + b64 + k0, &BsL[b][2048 + wid * 512]);
    }
  };

  f32x4 zero = {0.f, 0.f, 0.f, 0.f};
  f32x4 acc[4][NFR];
  #pragma unroll
  for (int i = 0; i < 4; i++)
    #pragma unroll
    for (int j = 0; j < NFR; j++) acc[i][j] = zero;

  int fr = lane & 15, g = lane >> 4;
  int cb = wc * (NT / 2);
  int nk = K >> 5;

  issue(0, 0);
  for (int ks = 0; ks < nk; ks++) {
    int cur = ks & 1;
    if (ks + 1 < nk) {
      issue((ks + 1) << 5, cur ^ 1);
      if constexpr (NT == 128) VMW(8); else VMW(6);  // waits exactly issue(ks)
    } else {
      VMW(0);
    }
    RBAR(); SCHB();
    bf16x8 afh[4], afl[4], bfh[NFR], bfl[NFR];
    #pragma unroll
    for (int i = 0; i < 4; i++) {
      afh[i] = *(const bf16x8*)(&AsH[cur][gsw2(wr * 64 + i * 16 + fr, g)]);
      afl[i] = *(const bf16x8*)(&AsL[cur][gsw2(wr * 64 + i * 16 + fr, g)]);
    }
    #pragma unroll
    for (int i = 0; i < NFR; i++) {
      bfh[i] = *(const bf16x8*)(&BsH[cur][gsw2(cb + i * 16 + fr, g)]);
      bfl[i] = *(const bf16x8*)(&BsL[cur][gsw2(cb + i * 16 + fr, g)]);
    }
    #pragma unroll
    for (int mi = 0; mi < 4; mi++)
      #pragma unroll
      for (int ni = 0; ni < NFR; ni++) {
        acc[mi][ni] = MFMA_BF16(afh[mi], bfh[ni], acc[mi][ni]);
        acc[mi][ni] = MFMA_BF16(afl[mi], bfh[ni], acc[mi][ni]);
        acc[mi][ni] = MFMA_BF16(afh[mi], bfl[ni], acc[mi][ni]);
      }
    RBAR();
  }

  #pragma unroll
  for (int mi = 0; mi < 4; mi++) {
    #pragma unroll
    for (int ni = 0; ni < NFR; ni++) {
      int mrow = m0 + wr * 64 + mi * 16 + ((lane >> 4) << 2);
      int ocol = n0 + cb + ni * 16 + fr;
      if constexpr (EPI == 0) {          // fused QKV
        float bb = b0[ocol];
        if (ocol < 512) {
          bf16* Dh = (ocol < 256) ? o0 : o2;
          bf16* Dl = (ocol < 256) ? o1 : o3;
          int oo = ocol & 255;
          #pragma unroll
          for (int r = 0; r < 4; r++) {
            unsigned short hi, lo;
            tsplit(acc[mi][ni][r] + bb, hi, lo);
            Dh[(size_t)(mrow + r) * 256 + oo] = hi;
            Dl[(size_t)(mrow + r) * 256 + oo] = lo;
          }
        } else {
          int c = ocol - 512;
          int dbi = mrow >> 11, nn = mrow & 2047;
          u16x4 ph, pl;
          #pragma unroll
          for (int r = 0; r < 4; r++) {
            unsigned short hi, lo;
            tsplit(acc[mi][ni][r] + bb, hi, lo);
            ph[r] = hi; pl[r] = lo;
          }
          *(u16x4*)(&o4[((size_t)dbi * 256 + c) * 2048 + nn]) = ph;
          *(u16x4*)(&o5[((size_t)dbi * 256 + c) * 2048 + nn]) = pl;
        }
      } else if constexpr (EPI == 2) {   // merge -> msg hi+lo
        float bb = b0[ocol];
        #pragma unroll
        for (int r = 0; r < 4; r++) {
          unsigned short hi, lo;
          tsplit(acc[mi][ni][r] + bb, hi, lo);
          o0[(size_t)(mrow + r) * 512 + 256 + ocol] = hi;
          o1[(size_t)(mrow + r) * 512 + 256 + ocol] = lo;
        }
      } else if constexpr (EPI == 3) {   // BN+ReLU hi+lo
        float ge = b0[ocol], be = b1[ocol];
        #pragma unroll
        for (int r = 0; r < 4; r++) {
          unsigned short hi, lo;
          tsplit(fmaxf(ge * acc[mi][ni][r] + be, 0.f), hi, lo);
          o0[(size_t)(mrow + r) * 512 + ocol] = hi;
          o1[(size_t)(mrow + r) * 512 + ocol] = lo;
        }
      } else {                           // EPI 4: residual
        float bb = b0[ocol];
        #pragma unroll
        for (int r = 0; r < 4; r++) {
          size_t ix = (size_t)(mrow + r) * 256 + ocol;
          float d = of[ix] + acc[mi][ni][r] + bb;
          of[ix] = d;
          unsigned short hi, lo;
          tsplit(d, hi, lo);
          o0[(size_t)(mrow + r) * 512 + ocol] = hi;
          o1[(size_t)(mrow + r) * 512 + ocol] = lo;
        }
      }
    }
  }
}

// ---------------------------------------------------------------------------
// Flash attention (round-8 structure): split-KV (2 halves), 8 waves x 16 rows,
// 3-term QK^T/PV, 3-phase pipelined, defer-max. FIX: loop-top wait is VMW(4)
// (wait K(t) only; leave all 4 V(t) loads in flight through QK^T+softmax).
// ---------------------------------------------------------------------------
DEVFN int swz(int row, int col) { return row * 64 + (col ^ ((row & 7) << 3)); }

__global__ __launch_bounds__(512, 4) void attn3s(
    const bf16* __restrict__ Qh, const bf16* __restrict__ Ql,
    const bf16* __restrict__ Kh, const bf16* __restrict__ Kl,
    const bf16* __restrict__ Vth, const bf16* __restrict__ Vtl,
    float* __restrict__ Pacc, float* __restrict__ Ml, int cross)
{
  __shared__ bf16 Ksh[64 * 64];
  __shared__ bf16 Ksl[64 * 64];
  __shared__ bf16 Vsh[64 * 64];
  __shared__ bf16 Vsl[64 * 64];
  __shared__ bf16 Psh[8][1024];
  __shared__ bf16 Psl[8][1024];
  int tid = threadIdx.x, lane = tid & 63, w = tid >> 6;
  int inst = blockIdx.y;
  int half = blockIdx.z;
  int db = inst >> 2, hd = inst & 3;
  int dsc = db >> 1, bi = db & 1;
  int sdb = (cross ? (1 - dsc) : dsc) * 2 + bi;
  size_t xq = (size_t)db * 2048;
  size_t xs = (size_t)sdb * 2048 + half * 1024;
  int n0 = blockIdx.x * 128;

  int fr = lane & 15, kof = (lane >> 4) << 3;

  // Q fragments hi/lo: direct global -> registers
  bf16x8 aqh[2], aql[2];
  #pragma unroll
  for (int kf = 0; kf < 2; kf++) {
    size_t g = (xq + n0 + w * 16 + fr) * 256 + hd * 64 + kf * 32 + kof;
    aqh[kf] = *(const bf16x8*)(Qh + g);
    aql[kf] = *(const bf16x8*)(Ql + g);
  }

  f32x4 zero = {0.f, 0.f, 0.f, 0.f};
  f32x4 oacc[4];
  #pragma unroll
  for (int ni = 0; ni < 4; ni++) oacc[ni] = zero;
  float mrun[4], lrun[4];
  #pragma unroll
  for (int r = 0; r < 4; r++) { mrun[r] = -3.0e38f; lrun[r] = 0.f; }

  bf16x8 vone;
  #pragma unroll
  for (int i = 0; i < 8; i++) vone[i] = (short)0x3F80;  // bf16 1.0

  // staging sources (pre-swizzled): lane -> row w*8 + (lane>>3),
  // granule (lane&7) ^ (row&7)  (lanes 0-7 = one row, 128B contiguous)
  int lrow = lane >> 3;
  int g8 = ((lane & 7) ^ (lrow & 7)) << 3;
  int krow = w * 8 + lrow;
  const bf16* Ksrc_h = Kh + (xs + krow) * 256 + hd * 64 + g8;
  const bf16* Ksrc_l = Kl + (xs + krow) * 256 + hd * 64 + g8;
  const bf16* Vsrc_h = Vth + ((size_t)sdb * 256 + hd * 64 + krow) * 2048 + half * 1024 + g8;
  const bf16* Vsrc_l = Vtl + ((size_t)sdb * 256 + hd * 64 + krow) * 2048 + half * 1024 + g8;
  bf16* LKh = Ksh + w * 512;
  bf16* LKl = Ksl + w * 512;
  bf16* LVh = Vsh + w * 512;
  bf16* LVl = Vsl + w * 512;

  // prologue: K(0) then V(0) in flight
  gll16(Ksrc_h, LKh);
  gll16(Ksrc_l, LKl);
  gll16(Vsrc_h, LVh);
  gll16(Vsrc_l, LVl);

  for (int t = 0; t < 16; t++) {
    VMW(4);            // K(t) landed; all 4 V(t) loads stay in flight
    RBAR(); SCHB();

    // ---- QK^T (3-term) ----
    f32x4 sacc[4];
    #pragma unroll
    for (int ni = 0; ni < 4; ni++) sacc[ni] = zero;
    #pragma unroll
    for (int kf = 0; kf < 2; kf++) {
      #pragma unroll
      for (int ni = 0; ni < 4; ni++) {
        bf16x8 bkh = *(const bf16x8*)(&Ksh[swz(ni * 16 + fr, kf * 32 + kof)]);
        bf16x8 bkl = *(const bf16x8*)(&Ksl[swz(ni * 16 + fr, kf * 32 + kof)]);
        sacc[ni] = MFMA_BF16(aqh[kf], bkh, sacc[ni]);
        sacc[ni] = MFMA_BF16(aql[kf], bkh, sacc[ni]);
        sacc[ni] = MFMA_BF16(aqh[kf], bkl, sacc[ni]);
      }
    }

    // ---- online softmax with defer-max (T13, exp2 units, THR=8) ----
    float tmr[4];
    bool need = false;
    #pragma unroll
    for (int r = 0; r < 4; r++) {
      float tm = fmaxf(fmaxf(sacc[0][r], sacc[1][r]), fmaxf(sacc[2][r], sacc[3][r]));
      tm = fmaxf(tm, __shfl_xor(tm, 1));
      tm = fmaxf(tm, __shfl_xor(tm, 2));
      tm = fmaxf(tm, __shfl_xor(tm, 4));
      tm = fmaxf(tm, __shfl_xor(tm, 8));
      tmr[r] = tm;
      need = need || (tm > mrun[r] + 8.0f);
    }
    if (__ballot(need)) {
      #pragma unroll
      for (int r = 0; r < 4; r++) {
        float mn = fmaxf(mrun[r], tmr[r]);
        float s = exp2f(mrun[r] - mn);
        mrun[r] = mn;
        lrun[r] *= s;
        #pragma unroll
        for (int ni = 0; ni < 4; ni++) oacc[ni][r] *= s;
      }
    }
    #pragma unroll
    for (int r = 0; r < 4; r++)
      #pragma unroll
      for (int ni = 0; ni < 4; ni++)
        sacc[ni][r] = exp2f(sacc[ni][r] - mrun[r]);

    VMW(0);            // V(t) landed (had QK^T+softmax to cover)
    RBAR(); SCHB();    // also: all waves finished QK^T -> K LDS free

    if (t + 1 < 16) {  // K(t+1) flies under P-store + PV
      gll16(Ksrc_h + (size_t)(t + 1) * 16384, LKh);
      gll16(Ksrc_l + (size_t)(t + 1) * 16384, LKl);
    }

    // ---- P -> LDS (own wave region) ----
    bf16* Pwh = &Psh[w][0];
    bf16* Pwl = &Psl[w][0];
    #pragma unroll
    for (int ni = 0; ni < 4; ni++) {
      int col = ni * 16 + fr;
      #pragma unroll
      for (int r = 0; r < 4; r++) {
        int row = ((lane >> 4) << 2) + r;
        unsigned short hi, lo;
        tsplit(sacc[ni][r], hi, lo);
        Pwh[swz(row, col)] = hi;
        Pwl[swz(row, col)] = lo;
      }
    }

    // ---- PV (3-term) + row-sum via ones-MFMA ----
    f32x4 racc = zero;
    #pragma unroll
    for (int kf = 0; kf < 2; kf++) {
      bf16x8 pah = *(const bf16x8*)(&Pwh[swz(fr, kf * 32 + kof)]);
      bf16x8 pal = *(const bf16x8*)(&Pwl[swz(fr, kf * 32 + kof)]);
      #pragma unroll
      for (int ni = 0; ni < 4; ni++) {
        bf16x8 bvh = *(const bf16x8*)(&Vsh[swz(ni * 16 + fr, kf * 32 + kof)]);
        bf16x8 bvl = *(const bf16x8*)(&Vsl[swz(ni * 16 + fr, kf * 32 + kof)]);
        oacc[ni] = MFMA_BF16(pah, bvh, oacc[ni]);
        oacc[ni] = MFMA_BF16(pal, bvh, oacc[ni]);
        oacc[ni] = MFMA_BF16(pah, bvl, oacc[ni]);
      }
      racc = MFMA_BF16(pah, vone, racc);
      racc = MFMA_BF16(pal, vone, racc);
    }
    #pragma unroll
    for (int r = 0; r < 4; r++)
      lrun[r] += racc[r];

    RBAR();            // all waves done PV -> V LDS free
    if (t + 1 < 16) {  // V(t+1) flies under next QK^T + softmax
      gll16(Vsrc_h + (t + 1) * 64, LVh);
      gll16(Vsrc_l + (t + 1) * 64, LVl);
    }
  }

  // store unnormalized partial O (fp32) + per-row (m, l)
  float* Pb = Pacc + (size_t)half * 8192 * 256;
  #pragma unroll
  for (int r = 0; r < 4; r++) {
    int nrow = n0 + w * 16 + ((lane >> 4) << 2) + r;
    size_t row = xq + nrow;
    #pragma unroll
    for (int ni = 0; ni < 4; ni++)
      Pb[row * 256 + hd * 64 + ni * 16 + fr] = oacc[ni][r];
    if (fr == 0) {
      float* mp = Ml + ((row * 4 + hd) << 2) + half * 2;
      mp[0] = mrun[r];
      mp[1] = lrun[r];
    }
  }
}

// ---------------------------------------------------------------------------
// Combine the two KV halves: O = (Pa*wa + Pb*wb) / (la*wa + lb*wb), hi/lo out.
// ---------------------------------------------------------------------------
__global__ __launch_bounds__(256) void attn_combine(
    const float* __restrict__ Pacc, const float* __restrict__ Ml,
    bf16* __restrict__ Oh, bf16* __restrict__ Ol)
{
  int tid = threadIdx.x, lane = tid & 63, w = tid >> 6;
  size_t row = (size_t)blockIdx.x * 4 + w;
  int hd = lane >> 4;
  int c0 = lane * 4;
  const float* mp = Ml + ((row * 4 + hd) << 2);
  float ma = mp[0], la = mp[1], mb = mp[2], lb = mp[3];
  float m = fmaxf(ma, mb);
  float wa = exp2f(ma - m), wb = exp2f(mb - m);
  float inv = 1.0f / (la * wa + lb * wb);
  wa *= inv; wb *= inv;
  f32x4 pa = *(const f32x4*)(Pacc + row * 256 + c0);
  f32x4 pb = *(const f32x4*)(Pacc + (size_t)8192 * 256 + row * 256 + c0);
  u16x4 vh, vl;
  #pragma unroll
  for (int r = 0; r < 4; r++) {
    unsigned short hi, lo;
    tsplit(pa[r] * wa + pb[r] * wb, hi, lo);
    vh[r] = hi; vl[r] = lo;
  }
  *(u16x4*)(Oh + row * 256 + c0) = vh;
  *(u16x4*)(Ol + row * 256 + c0) = vl;
}

// ---------------------------------------------------------------------------
extern "C" void kernel_launch(void* const* d_in, const int* in_sizes, int n_in,
                              void* d_out, int out_size, void* d_ws, size_t ws_size,
                              hipStream_t stream)
{
  (void)in_sizes; (void)n_in; (void)out_size; (void)ws_size;
  const float* desc0 = (const float*)d_in[0];
  const float* desc1 = (const float*)d_in[1];
  const float* Wq = (const float*)d_in[2];
  const float* bq = (const float*)d_in[3];
  const float* Wk = (const float*)d_in[4];
  const float* bk = (const float*)d_in[5];
  const float* Wv = (const float*)d_in[6];
  const float* bv = (const float*)d_in[7];
  const float* Wm = (const float*)d_in[8];
  const float* bm = (const float*)d_in[9];
  const float* W1 = (const float*)d_in[10];
  const float* b1 = (const float*)d_in[11];
  const float* gm = (const float*)d_in[12];
  const float* bt = (const float*)d_in[13];
  const float* W2 = (const float*)d_in[14];
  const float* b2 = (const float*)d_in[15];
  float* out = (float*)d_out;

  char* ws = (char*)d_ws;
  bf16*  Wbf  = (bf16*)(ws + 0);            //  31,457,280
  float* bias = (float*)(ws + 31457280);    //     110,592
  float* Dm   = (float*)(ws + 31567872);    //  16,777,216  fp32 master [xi,256]
  bf16*  Hin  = (bf16*)(ws + 48345088);     //  16,777,216  [xi,512] = xh | msg_h
  bf16*  XMl  = (bf16*)(ws + 65122304);     //  16,777,216  [xi,512] = xl | msg_l
  bf16*  Qh   = (bf16*)(ws + 81899520);     //   8,388,608
  bf16*  Ql   = (bf16*)(ws + 90288128);     //   8,388,608
  bf16*  Kh   = (bf16*)(ws + 98676736);     //   8,388,608
  bf16*  Kl   = (bf16*)(ws + 107065344);    //   8,388,608
  bf16*  Vth  = (bf16*)(ws + 115453952);    //   8,388,608  [db,256,2048]
  bf16*  Vtl  = (bf16*)(ws + 123842560);    //   8,388,608
  bf16*  Oh   = (bf16*)(ws + 132231168);    //   8,388,608
  bf16*  Ol   = (bf16*)(ws + 140619776);    //   8,388,608
  float* Pacc = (float*)(ws + 149008384);   //  16,777,216  [2][8192][256] fp32
  float* Ml   = (float*)(ws + 165785600);   //     524,288  [8192][4][4]
  // end: 166,309,888
  bf16*  Hbh  = Qh;                         // alias Qh+Ql (disjoint in time)
  bf16*  Hbl  = Kh;                         // alias Kh+Kl

  prep_weights<<<dim3(5130, 12), 256, 0, stream>>>(Wq, bq, Wk, bk, Wv, bv, Wm, bm,
                                                   W1, b1, gm, bt, W2, b2, Wbf, bias);
  transpose_in<<<dim3(64, 8, 4), dim3(32, 8), 0, stream>>>(desc0, desc1, Dm, Hin, XMl);

  for (int l = 0; l < NL; l++) {
    const bf16* wl = Wbf + (size_t)l * 1310720;
    const float* bl = bias + l * 2304;
    int cross = l & 1;
    // fused QKV (Q pre-scaled by log2e/8)
    gemm3<0, 128><<<dim3(64, 6), 256, 0, stream>>>(Hin, 512, XMl, 512,
        wl, wl + 196608, 256, bl, nullptr,
        Qh, Ql, Kh, Kl, Vth, Vtl, nullptr);
    // split-KV attention + combine
    attn3s<<<dim3(16, 16, 2), 512, 0, stream>>>(Qh, Ql, Kh, Kl, Vth, Vtl,
                                                Pacc, Ml, cross);
    attn_combine<<<2048, 256, 0, stream>>>(Pacc, Ml, Oh, Ol);
    // merge: msg = O·Wm^T
    gemm3<2, 64><<<dim3(64, 4), 256, 0, stream>>>(Oh, 256, Ol, 256,
        wl + 393216, wl + 458752, 256, bl + 768, nullptr,
        Hin, XMl, nullptr, nullptr, nullptr, nullptr, nullptr);
    // MLP1 + BN + ReLU
    gemm3<3, 128><<<dim3(64, 4), 256, 0, stream>>>(Hin, 512, XMl, 512,
        wl + 524288, wl + 786432, 512, bl + 1024, bl + 1536,
        Hbh, Hbl, nullptr, nullptr, nullptr, nullptr, nullptr);
    // MLP2 + residual
    gemm3<4, 64><<<dim3(64, 4), 256, 0, stream>>>(Hbh, 512, Hbl, 512,
        wl + 1048576, wl + 1179648, 512, bl + 2048, nullptr,
        Hin, XMl, nullptr, nullptr, nullptr, nullptr, Dm);
  }
  transpose_out<<<dim3(64, 8, 4), dim3(32, 8), 0, stream>>>(Dm, out);
}

// Round 13
// 1734.992 us; speedup vs baseline: 1.4890x; 1.0782x over previous
//
#include <hip/hip_runtime.h>

typedef unsigned short bf16;
typedef __attribute__((ext_vector_type(8))) short bf16x8;
typedef __attribute__((ext_vector_type(4))) float f32x4;
typedef unsigned short u16x4 __attribute__((ext_vector_type(4)));

#define DEVFN static __device__ __forceinline__

#define NL 12

#define VMW(N) asm volatile("s_waitcnt vmcnt(" #N ")" ::: "memory")
#define RBAR() asm volatile("s_barrier" ::: "memory")
#define SCHB() __builtin_amdgcn_sched_barrier(0)

DEVFN unsigned short f2bf(float f) {
  union { float f; unsigned u; } v; v.f = f;
  unsigned u = v.u;
  unsigned r = (u + 0x7fffu + ((u >> 16) & 1u)) >> 16;  // RNE
  return (unsigned short)r;
}
DEVFN float bf2f(unsigned short h) {
  union { unsigned u; float f; } v; v.u = ((unsigned)h) << 16; return v.f;
}
// truncation hi/lo split: 4 ALU ops, pair error ~2^-18
DEVFN void tsplit(float v, unsigned short& h, unsigned short& l) {
  union { float f; unsigned u; } a; a.f = v;
  h = (unsigned short)(a.u >> 16);
  union { float f; unsigned u; } b; b.u = a.u & 0xffff0000u;
  union { float f; unsigned u; } c; c.f = v - b.f;
  l = (unsigned short)(c.u >> 16);
}
// async global->LDS, 16B per lane; dest = wave-uniform base + lane*16
DEVFN void gll16(const bf16* g, bf16* l) {
  __builtin_amdgcn_global_load_lds(
      (const __attribute__((address_space(1))) unsigned int*)g,
      (__attribute__((address_space(3))) unsigned int*)l, 16, 0, 0);
}

#define MFMA_BF16(a, b, c) __builtin_amdgcn_mfma_f32_16x16x32_bf16((a), (b), (c), 0, 0, 0)

// ---------------------------------------------------------------------------
// Weight prep: hi/lo bf16 split (RNE). Wq/bq folded with Cs = log2(e)/8.
// Per-layer bf16 block (1310720):
//   [0,196608) Wqkv hi | [196608,393216) Wqkv lo | [393216,458752) Wm hi (unused)
//   [458752,524288) Wm lo (unused) | [524288,786432) W1eff hi |
//   [786432,1048576) W1eff lo | [1048576,1179648) W2 hi | [1179648,1310720) W2 lo
// W1eff cols 256:512 are OVERWRITTEN by prep_fold with E = W1b·WmH.
// f32 bias block (2304): bqkv[768] | bm[256] | geff[512] | beff[512] | b2[256]
// beff gets += geff·(W1b·bm) in prep_fold.
// ---------------------------------------------------------------------------
__global__ void prep_weights(const float* __restrict__ Wq, const float* __restrict__ bq,
                             const float* __restrict__ Wk, const float* __restrict__ bk,
                             const float* __restrict__ Wv, const float* __restrict__ bv,
                             const float* __restrict__ Wm, const float* __restrict__ bm,
                             const float* __restrict__ W1, const float* __restrict__ b1,
                             const float* __restrict__ gm, const float* __restrict__ bt,
                             const float* __restrict__ W2, const float* __restrict__ b2,
                             bf16* __restrict__ Wbf, float* __restrict__ bias)
{
  int l = blockIdx.y;
  bf16* wl = Wbf + (size_t)l * 1310720;
  float* bl = bias + l * 2304;
  int idx = blockIdx.x * blockDim.x + threadIdx.x;
  if (idx >= 1310720 + 2304) return;
  const float INV = 1.0f / sqrtf(1.0f + 1e-5f);
  const float Cs = 0.18033688011112042f;  // log2(e)/8

  float w = 0.f;
  int lo = 0;
  if (idx < 393216) {                         // Wqkv
    int j = idx; lo = (j >= 196608); j -= lo * 196608;
    int t = j >> 16;
    int p = (j >> 8) & 255;
    int k = j & 255;
    int c = ((p & 63) << 2) | (p >> 6);       // p = h*64+i -> c = i*4+h
    const float* W = (t == 0) ? Wq : (t == 1) ? Wk : Wv;
    w = W[(size_t)l * 65536 + c * 256 + k];
    if (t == 0) w *= Cs;
  } else if (idx < 524288) {                  // Wm (unused after fold; keep filled)
    int j = idx - 393216; lo = (j >= 65536); j -= lo * 65536;
    int o = j >> 8, p = j & 255;
    int c = ((p & 63) << 2) | (p >> 6);
    w = Wm[(size_t)l * 65536 + o * 256 + c];
  } else if (idx < 1048576) {                 // W1 (cols 256:512 overwritten later)
    int j = idx - 524288; lo = (j >= 262144); j &= 262143;
    w = W1[(size_t)l * 262144 + j];
  } else if (idx < 1310720) {                 // W2
    int j = idx - 1048576; lo = (j >= 131072); j &= 131071;
    w = W2[(size_t)l * 131072 + j];
  } else {
    int j = idx - 1310720;
    if (j < 768) {
      int t = j >> 8, p = j & 255;
      int c = ((p & 63) << 2) | (p >> 6);
      const float* bsrc = (t == 0) ? bq : (t == 1) ? bk : bv;
      bl[j] = bsrc[l * 256 + c] * ((t == 0) ? Cs : 1.0f);
    } else if (j < 1024) {
      bl[j] = bm[l * 256 + (j - 768)];
    } else if (j < 1536) {
      bl[j] = gm[l * 512 + (j - 1024)] * INV;
    } else if (j < 2048) {
      int o = j - 1536;
      bl[j] = gm[l * 512 + o] * INV * b1[l * 512 + o] + bt[l * 512 + o];
    } else {
      bl[j] = b2[l * 256 + (j - 2048)];
    }
    return;
  }
  unsigned short hi = f2bf(w);
  wl[idx] = lo ? f2bf(w - bf2f(hi)) : hi;
}

// ---------------------------------------------------------------------------
// Merge-GEMM fold: E[r][k] = sum_oc W1[r][256+oc] * Wm[oc][perm(k)]  (fp32),
// written hi/lo into W1eff cols 256:512; beff[r] += geff[r]*(W1b·bm)[r].
// grid (128, 12), 256 threads; block = 4 rows x 256 k-cols. Runs after
// prep_weights (stream-ordered overwrite), deterministic per replay.
// ---------------------------------------------------------------------------
__global__ void prep_fold(const float* __restrict__ W1, const float* __restrict__ Wm,
                          const float* __restrict__ bm,
                          bf16* __restrict__ Wbf, float* __restrict__ bias)
{
  int l = blockIdx.y;
  int r0 = blockIdx.x * 4;
  int k = threadIdx.x;
  int pk = ((k & 63) << 2) | (k >> 6);
  __shared__ float w1b[4][256];
  for (int j = threadIdx.x; j < 1024; j += 256)
    w1b[j >> 8][j & 255] = W1[(size_t)l * 262144 + (r0 + (j >> 8)) * 512 + 256 + (j & 255)];
  __syncthreads();
  float acc[4] = {0.f, 0.f, 0.f, 0.f};
  for (int oc = 0; oc < 256; oc++) {
    float wv = Wm[(size_t)l * 65536 + oc * 256 + pk];
    acc[0] += w1b[0][oc] * wv;
    acc[1] += w1b[1][oc] * wv;
    acc[2] += w1b[2][oc] * wv;
    acc[3] += w1b[3][oc] * wv;
  }
  bf16* wl = Wbf + (size_t)l * 1310720;
  #pragma unroll
  for (int j = 0; j < 4; j++) {
    unsigned short hi = f2bf(acc[j]);
    wl[524288 + (size_t)(r0 + j) * 512 + 256 + k] = hi;
    wl[786432 + (size_t)(r0 + j) * 512 + 256 + k] = f2bf(acc[j] - bf2f(hi));
  }
  if (threadIdx.x < 4) {
    int j = threadIdx.x;
    float d = 0.f;
    for (int oc = 0; oc < 256; oc++) d += w1b[j][oc] * bm[l * 256 + oc];
    float ge = bias[l * 2304 + 1024 + r0 + j];
    bias[l * 2304 + 1536 + r0 + j] += ge * d;   // unique writer per row
  }
}

// ---------------------------------------------------------------------------
__global__ void transpose_in(const float* __restrict__ s0, const float* __restrict__ s1,
                             float* __restrict__ Dm, bf16* __restrict__ Hin,
                             bf16* __restrict__ XMl)
{
  __shared__ float t[32][33];
  int db = blockIdx.z;
  int dsc = db >> 1, bi = db & 1;
  const float* src = dsc ? s1 : s0;
  int n0 = blockIdx.x * 32, d0 = blockIdx.y * 32;
  int tx = threadIdx.x, ty = threadIdx.y;
  #pragma unroll
  for (int i = 0; i < 32; i += 8)
    t[ty + i][tx] = src[(size_t)(bi * 256 + d0 + ty + i) * 2048 + n0 + tx];
  __syncthreads();
  #pragma unroll
  for (int i = 0; i < 32; i += 8) {
    size_t xi = (size_t)db * 2048 + n0 + ty + i;
    float v = t[tx][ty + i];
    Dm[xi * 256 + d0 + tx] = v;
    unsigned short hi, lo;
    tsplit(v, hi, lo);
    Hin[xi * 512 + d0 + tx] = hi;
    XMl[xi * 512 + d0 + tx] = lo;
  }
}

__global__ void transpose_out(const float* __restrict__ Dm, float* __restrict__ out)
{
  __shared__ float t[32][33];
  int db = blockIdx.z;
  int n0 = blockIdx.x * 32, d0 = blockIdx.y * 32;
  int tx = threadIdx.x, ty = threadIdx.y;
  #pragma unroll
  for (int i = 0; i < 32; i += 8)
    t[ty + i][tx] = Dm[((size_t)db * 2048 + n0 + ty + i) * 256 + d0 + tx];
  __syncthreads();
  #pragma unroll
  for (int i = 0; i < 32; i += 8)
    out[(size_t)(db * 256 + d0 + ty + i) * 2048 + n0 + tx] = t[tx][ty + i];
}

// ---------------------------------------------------------------------------
// 3-term split GEMM (round-12 structure): tile 128xNT, BK=32, 4 waves,
// double-buffered global_load_lds, counted vmcnt + raw bars, sigma-swizzle
// gsw2 (coalesced staging quads + conflict-free reads).
// ---------------------------------------------------------------------------
DEVFN int gsw2(int row, int g) { return row * 32 + (((g ^ (row >> 1)) & 3) << 3); }

template<int EPI, int NT>
__global__ __launch_bounds__(256, (NT == 128) ? 2 : 3) void gemm3(
    const bf16* __restrict__ Ah, int lda,
    const bf16* __restrict__ Al, int ldal,
    const bf16* __restrict__ Wh, const bf16* __restrict__ Wl, int K,
    const float* __restrict__ b0, const float* __restrict__ b1,
    bf16* __restrict__ o0, bf16* __restrict__ o1,
    bf16* __restrict__ o2, bf16* __restrict__ o3,
    bf16* __restrict__ o4, bf16* __restrict__ o5,
    float* __restrict__ of)
{
  constexpr int NFR = NT / 32;
  __shared__ bf16 AsH[2][4096];
  __shared__ bf16 AsL[2][4096];
  __shared__ bf16 BsH[2][NT * 32];
  __shared__ bf16 BsL[2][NT * 32];
  int tid = threadIdx.x, lane = tid & 63, wid = tid >> 6;
  int wr = wid >> 1, wc = wid & 1;
  int m0 = blockIdx.x * 128, n0 = blockIdx.y * NT;

  int lrow = lane >> 2;
  int g4 = (((lane & 3) ^ (lane >> 3)) & 3) << 3;
  const bf16* A0h = Ah + (size_t)(m0 + wid * 16 + lrow) * lda + g4;
  const bf16* A0l = Al + (size_t)(m0 + wid * 16 + lrow) * ldal + g4;
  const bf16* B0h = Wh + (size_t)(n0 + wid * 16 + lrow) * K + g4;
  const bf16* B0l = Wl + (size_t)(n0 + wid * 16 + lrow) * K + g4;
  size_t a64h = (size_t)64 * lda, a64l = (size_t)64 * ldal, b64 = (size_t)64 * K;

  auto issue = [&](int k0, int b) {
    gll16(A0h + k0, &AsH[b][wid * 512]);
    gll16(A0h + a64h + k0, &AsH[b][2048 + wid * 512]);
    gll16(A0l + k0, &AsL[b][wid * 512]);
    gll16(A0l + a64l + k0, &AsL[b][2048 + wid * 512]);
    gll16(B0h + k0, &BsH[b][wid * 512]);
    gll16(B0l + k0, &BsL[b][wid * 512]);
    if constexpr (NT == 128) {
      gll16(B0h + b64 + k0, &BsH[b][2048 + wid * 512]);
      gll16(B0l + b64 + k0, &BsL[b][2048 + wid * 512]);
    }
  };

  f32x4 zero = {0.f, 0.f, 0.f, 0.f};
  f32x4 acc[4][NFR];
  #pragma unroll
  for (int i = 0; i < 4; i++)
    #pragma unroll
    for (int j = 0; j < NFR; j++) acc[i][j] = zero;

  int fr = lane & 15, g = lane >> 4;
  int cb = wc * (NT / 2);
  int nk = K >> 5;

  issue(0, 0);
  for (int ks = 0; ks < nk; ks++) {
    int cur = ks & 1;
    if (ks + 1 < nk) {
      issue((ks + 1) << 5, cur ^ 1);
      if constexpr (NT == 128) VMW(8); else VMW(6);
    } else {
      VMW(0);
    }
    RBAR(); SCHB();
    bf16x8 afh[4], afl[4], bfh[NFR], bfl[NFR];
    #pragma unroll
    for (int i = 0; i < 4; i++) {
      afh[i] = *(const bf16x8*)(&AsH[cur][gsw2(wr * 64 + i * 16 + fr, g)]);
      afl[i] = *(const bf16x8*)(&AsL[cur][gsw2(wr * 64 + i * 16 + fr, g)]);
    }
    #pragma unroll
    for (int i = 0; i < NFR; i++) {
      bfh[i] = *(const bf16x8*)(&BsH[cur][gsw2(cb + i * 16 + fr, g)]);
      bfl[i] = *(const bf16x8*)(&BsL[cur][gsw2(cb + i * 16 + fr, g)]);
    }
    #pragma unroll
    for (int mi = 0; mi < 4; mi++)
      #pragma unroll
      for (int ni = 0; ni < NFR; ni++) {
        acc[mi][ni] = MFMA_BF16(afh[mi], bfh[ni], acc[mi][ni]);
        acc[mi][ni] = MFMA_BF16(afl[mi], bfh[ni], acc[mi][ni]);
        acc[mi][ni] = MFMA_BF16(afh[mi], bfl[ni], acc[mi][ni]);
      }
    RBAR();
  }

  #pragma unroll
  for (int mi = 0; mi < 4; mi++) {
    #pragma unroll
    for (int ni = 0; ni < NFR; ni++) {
      int mrow = m0 + wr * 64 + mi * 16 + ((lane >> 4) << 2);
      int ocol = n0 + cb + ni * 16 + fr;
      if constexpr (EPI == 0) {          // fused QKV
        float bb = b0[ocol];
        if (ocol < 512) {
          bf16* Dh = (ocol < 256) ? o0 : o2;
          bf16* Dl = (ocol < 256) ? o1 : o3;
          int oo = ocol & 255;
          #pragma unroll
          for (int r = 0; r < 4; r++) {
            unsigned short hi, lo;
            tsplit(acc[mi][ni][r] + bb, hi, lo);
            Dh[(size_t)(mrow + r) * 256 + oo] = hi;
            Dl[(size_t)(mrow + r) * 256 + oo] = lo;
          }
        } else {
          int c = ocol - 512;
          int dbi = mrow >> 11, nn = mrow & 2047;
          u16x4 ph, pl;
          #pragma unroll
          for (int r = 0; r < 4; r++) {
            unsigned short hi, lo;
            tsplit(acc[mi][ni][r] + bb, hi, lo);
            ph[r] = hi; pl[r] = lo;
          }
          *(u16x4*)(&o4[((size_t)dbi * 256 + c) * 2048 + nn]) = ph;
          *(u16x4*)(&o5[((size_t)dbi * 256 + c) * 2048 + nn]) = pl;
        }
      } else if constexpr (EPI == 3) {   // BN+ReLU hi+lo
        float ge = b0[ocol], be = b1[ocol];
        #pragma unroll
        for (int r = 0; r < 4; r++) {
          unsigned short hi, lo;
          tsplit(fmaxf(ge * acc[mi][ni][r] + be, 0.f), hi, lo);
          o0[(size_t)(mrow + r) * 512 + ocol] = hi;
          o1[(size_t)(mrow + r) * 512 + ocol] = lo;
        }
      } else {                           // EPI 4: residual
        float bb = b0[ocol];
        #pragma unroll
        for (int r = 0; r < 4; r++) {
          size_t ix = (size_t)(mrow + r) * 256 + ocol;
          float d = of[ix] + acc[mi][ni][r] + bb;
          of[ix] = d;
          unsigned short hi, lo;
          tsplit(d, hi, lo);
          o0[(size_t)(mrow + r) * 512 + ocol] = hi;
          o1[(size_t)(mrow + r) * 512 + ocol] = lo;
        }
      }
    }
  }
}

// ---------------------------------------------------------------------------
// Flash attention (round-12 structure) + cheap softmax check: steady-state
// tiles do 3 per-lane fmax + ballot; the 16-shfl row-reduce + rescale runs
// only when some lane's local max exceeds mrun+8 (tile 0, rare jumps).
// ---------------------------------------------------------------------------
DEVFN int swz(int row, int col) { return row * 64 + (col ^ ((row & 7) << 3)); }

__global__ __launch_bounds__(512, 4) void attn3s(
    const bf16* __restrict__ Qh, const bf16* __restrict__ Ql,
    const bf16* __restrict__ Kh, const bf16* __restrict__ Kl,
    const bf16* __restrict__ Vth, const bf16* __restrict__ Vtl,
    float* __restrict__ Pacc, float* __restrict__ Ml, int cross)
{
  __shared__ bf16 Ksh[64 * 64];
  __shared__ bf16 Ksl[64 * 64];
  __shared__ bf16 Vsh[64 * 64];
  __shared__ bf16 Vsl[64 * 64];
  __shared__ bf16 Psh[8][1024];
  __shared__ bf16 Psl[8][1024];
  int tid = threadIdx.x, lane = tid & 63, w = tid >> 6;
  int inst = blockIdx.y;
  int half = blockIdx.z;
  int db = inst >> 2, hd = inst & 3;
  int dsc = db >> 1, bi = db & 1;
  int sdb = (cross ? (1 - dsc) : dsc) * 2 + bi;
  size_t xq = (size_t)db * 2048;
  size_t xs = (size_t)sdb * 2048 + half * 1024;
  int n0 = blockIdx.x * 128;

  int fr = lane & 15, kof = (lane >> 4) << 3;

  bf16x8 aqh[2], aql[2];
  #pragma unroll
  for (int kf = 0; kf < 2; kf++) {
    size_t g = (xq + n0 + w * 16 + fr) * 256 + hd * 64 + kf * 32 + kof;
    aqh[kf] = *(const bf16x8*)(Qh + g);
    aql[kf] = *(const bf16x8*)(Ql + g);
  }

  f32x4 zero = {0.f, 0.f, 0.f, 0.f};
  f32x4 oacc[4];
  #pragma unroll
  for (int ni = 0; ni < 4; ni++) oacc[ni] = zero;
  float mrun[4], lrun[4];
  #pragma unroll
  for (int r = 0; r < 4; r++) { mrun[r] = -3.0e38f; lrun[r] = 0.f; }

  bf16x8 vone;
  #pragma unroll
  for (int i = 0; i < 8; i++) vone[i] = (short)0x3F80;  // bf16 1.0

  int lrow = lane >> 3;
  int g8 = ((lane & 7) ^ (lrow & 7)) << 3;
  int krow = w * 8 + lrow;
  const bf16* Ksrc_h = Kh + (xs + krow) * 256 + hd * 64 + g8;
  const bf16* Ksrc_l = Kl + (xs + krow) * 256 + hd * 64 + g8;
  const bf16* Vsrc_h = Vth + ((size_t)sdb * 256 + hd * 64 + krow) * 2048 + half * 1024 + g8;
  const bf16* Vsrc_l = Vtl + ((size_t)sdb * 256 + hd * 64 + krow) * 2048 + half * 1024 + g8;
  bf16* LKh = Ksh + w * 512;
  bf16* LKl = Ksl + w * 512;
  bf16* LVh = Vsh + w * 512;
  bf16* LVl = Vsl + w * 512;

  gll16(Ksrc_h, LKh);
  gll16(Ksrc_l, LKl);
  gll16(Vsrc_h, LVh);
  gll16(Vsrc_l, LVl);

  for (int t = 0; t < 16; t++) {
    VMW(4);            // K(t) landed; V(t) loads stay in flight
    RBAR(); SCHB();

    // ---- QK^T (3-term) ----
    f32x4 sacc[4];
    #pragma unroll
    for (int ni = 0; ni < 4; ni++) sacc[ni] = zero;
    #pragma unroll
    for (int kf = 0; kf < 2; kf++) {
      #pragma unroll
      for (int ni = 0; ni < 4; ni++) {
        bf16x8 bkh = *(const bf16x8*)(&Ksh[swz(ni * 16 + fr, kf * 32 + kof)]);
        bf16x8 bkl = *(const bf16x8*)(&Ksl[swz(ni * 16 + fr, kf * 32 + kof)]);
        sacc[ni] = MFMA_BF16(aqh[kf], bkh, sacc[ni]);
        sacc[ni] = MFMA_BF16(aql[kf], bkh, sacc[ni]);
        sacc[ni] = MFMA_BF16(aqh[kf], bkl, sacc[ni]);
      }
    }

    // ---- cheap defer-max check (full reduce only when needed) ----
    float tml[4];
    bool need = false;
    #pragma unroll
    for (int r = 0; r < 4; r++) {
      tml[r] = fmaxf(fmaxf(sacc[0][r], sacc[1][r]), fmaxf(sacc[2][r], sacc[3][r]));
      need = need || (tml[r] > mrun[r] + 8.0f);
    }
    if (__ballot(need)) {
      #pragma unroll
      for (int r = 0; r < 4; r++) {
        float tm = tml[r];
        tm = fmaxf(tm, __shfl_xor(tm, 1));
        tm = fmaxf(tm, __shfl_xor(tm, 2));
        tm = fmaxf(tm, __shfl_xor(tm, 4));
        tm = fmaxf(tm, __shfl_xor(tm, 8));
        float mn = fmaxf(mrun[r], tm);
        float s = exp2f(mrun[r] - mn);
        mrun[r] = mn;
        lrun[r] *= s;
        #pragma unroll
        for (int ni = 0; ni < 4; ni++) oacc[ni][r] *= s;
      }
    }
    #pragma unroll
    for (int r = 0; r < 4; r++)
      #pragma unroll
      for (int ni = 0; ni < 4; ni++)
        sacc[ni][r] = exp2f(sacc[ni][r] - mrun[r]);

    VMW(0);            // V(t) landed
    RBAR(); SCHB();

    if (t + 1 < 16) {  // K(t+1) flies under P-store + PV
      gll16(Ksrc_h + (size_t)(t + 1) * 16384, LKh);
      gll16(Ksrc_l + (size_t)(t + 1) * 16384, LKl);
    }

    // ---- P -> LDS (own wave region) ----
    bf16* Pwh = &Psh[w][0];
    bf16* Pwl = &Psl[w][0];
    #pragma unroll
    for (int ni = 0; ni < 4; ni++) {
      int col = ni * 16 + fr;
      #pragma unroll
      for (int r = 0; r < 4; r++) {
        int row = ((lane >> 4) << 2) + r;
        unsigned short hi, lo;
        tsplit(sacc[ni][r], hi, lo);
        Pwh[swz(row, col)] = hi;
        Pwl[swz(row, col)] = lo;
      }
    }

    // ---- PV (3-term) + row-sum via ones-MFMA ----
    f32x4 racc = zero;
    #pragma unroll
    for (int kf = 0; kf < 2; kf++) {
      bf16x8 pah = *(const bf16x8*)(&Pwh[swz(fr, kf * 32 + kof)]);
      bf16x8 pal = *(const bf16x8*)(&Pwl[swz(fr, kf * 32 + kof)]);
      #pragma unroll
      for (int ni = 0; ni < 4; ni++) {
        bf16x8 bvh = *(const bf16x8*)(&Vsh[swz(ni * 16 + fr, kf * 32 + kof)]);
        bf16x8 bvl = *(const bf16x8*)(&Vsl[swz(ni * 16 + fr, kf * 32 + kof)]);
        oacc[ni] = MFMA_BF16(pah, bvh, oacc[ni]);
        oacc[ni] = MFMA_BF16(pal, bvh, oacc[ni]);
        oacc[ni] = MFMA_BF16(pah, bvl, oacc[ni]);
      }
      racc = MFMA_BF16(pah, vone, racc);
      racc = MFMA_BF16(pal, vone, racc);
    }
    #pragma unroll
    for (int r = 0; r < 4; r++)
      lrun[r] += racc[r];

    RBAR();
    if (t + 1 < 16) {  // V(t+1) flies under next QK^T + softmax
      gll16(Vsrc_h + (t + 1) * 64, LVh);
      gll16(Vsrc_l + (t + 1) * 64, LVl);
    }
  }

  float* Pb = Pacc + (size_t)half * 8192 * 256;
  #pragma unroll
  for (int r = 0; r < 4; r++) {
    int nrow = n0 + w * 16 + ((lane >> 4) << 2) + r;
    size_t row = xq + nrow;
    #pragma unroll
    for (int ni = 0; ni < 4; ni++)
      Pb[row * 256 + hd * 64 + ni * 16 + fr] = oacc[ni][r];
    if (fr == 0) {
      float* mp = Ml + ((row * 4 + hd) << 2) + half * 2;
      mp[0] = mrun[r];
      mp[1] = lrun[r];
    }
  }
}

// ---------------------------------------------------------------------------
// Combine the two KV halves; writes O directly into Hin/XMl cols 256:512
// (merge GEMM folded into MLP1 via W1eff).
// ---------------------------------------------------------------------------
__global__ __launch_bounds__(256) void attn_combine(
    const float* __restrict__ Pacc, const float* __restrict__ Ml,
    bf16* __restrict__ Hin, bf16* __restrict__ XMl)
{
  int tid = threadIdx.x, lane = tid & 63, w = tid >> 6;
  size_t row = (size_t)blockIdx.x * 4 + w;
  int hd = lane >> 4;
  int c0 = lane * 4;
  const float* mp = Ml + ((row * 4 + hd) << 2);
  float ma = mp[0], la = mp[1], mb = mp[2], lb = mp[3];
  float m = fmaxf(ma, mb);
  float wa = exp2f(ma - m), wb = exp2f(mb - m);
  float inv = 1.0f / (la * wa + lb * wb);
  wa *= inv; wb *= inv;
  f32x4 pa = *(const f32x4*)(Pacc + row * 256 + c0);
  f32x4 pb = *(const f32x4*)(Pacc + (size_t)8192 * 256 + row * 256 + c0);
  u16x4 vh, vl;
  #pragma unroll
  for (int r = 0; r < 4; r++) {
    unsigned short hi, lo;
    tsplit(pa[r] * wa + pb[r] * wb, hi, lo);
    vh[r] = hi; vl[r] = lo;
  }
  *(u16x4*)(Hin + row * 512 + 256 + c0) = vh;
  *(u16x4*)(XMl + row * 512 + 256 + c0) = vl;
}

// ---------------------------------------------------------------------------
extern "C" void kernel_launch(void* const* d_in, const int* in_sizes, int n_in,
                              void* d_out, int out_size, void* d_ws, size_t ws_size,
                              hipStream_t stream)
{
  (void)in_sizes; (void)n_in; (void)out_size; (void)ws_size;
  const float* desc0 = (const float*)d_in[0];
  const float* desc1 = (const float*)d_in[1];
  const float* Wq = (const float*)d_in[2];
  const float* bq = (const float*)d_in[3];
  const float* Wk = (const float*)d_in[4];
  const float* bk = (const float*)d_in[5];
  const float* Wv = (const float*)d_in[6];
  const float* bv = (const float*)d_in[7];
  const float* Wm = (const float*)d_in[8];
  const float* bm = (const float*)d_in[9];
  const float* W1 = (const float*)d_in[10];
  const float* b1 = (const float*)d_in[11];
  const float* gm = (const float*)d_in[12];
  const float* bt = (const float*)d_in[13];
  const float* W2 = (const float*)d_in[14];
  const float* b2 = (const float*)d_in[15];
  float* out = (float*)d_out;

  char* ws = (char*)d_ws;
  bf16*  Wbf  = (bf16*)(ws + 0);            //  31,457,280
  float* bias = (float*)(ws + 31457280);    //     110,592
  float* Dm   = (float*)(ws + 31567872);    //  16,777,216  fp32 master [xi,256]
  bf16*  Hin  = (bf16*)(ws + 48345088);     //  16,777,216  [xi,512] = xh | O_h
  bf16*  XMl  = (bf16*)(ws + 65122304);     //  16,777,216  [xi,512] = xl | O_l
  bf16*  Qh   = (bf16*)(ws + 81899520);     //   8,388,608
  bf16*  Ql   = (bf16*)(ws + 90288128);     //   8,388,608
  bf16*  Kh   = (bf16*)(ws + 98676736);     //   8,388,608
  bf16*  Kl   = (bf16*)(ws + 107065344);    //   8,388,608
  bf16*  Vth  = (bf16*)(ws + 115453952);    //   8,388,608  [db,256,2048]
  bf16*  Vtl  = (bf16*)(ws + 123842560);    //   8,388,608
  float* Pacc = (float*)(ws + 132231168);   //  16,777,216  [2][8192][256] fp32
  float* Ml   = (float*)(ws + 149008384);   //     524,288  [8192][4][4]
  // end: 149,532,672
  bf16*  Hbh  = Qh;                         // alias Qh+Ql (disjoint in time)
  bf16*  Hbl  = Kh;                         // alias Kh+Kl

  prep_weights<<<dim3(5130, 12), 256, 0, stream>>>(Wq, bq, Wk, bk, Wv, bv, Wm, bm,
                                                   W1, b1, gm, bt, W2, b2, Wbf, bias);
  prep_fold<<<dim3(128, 12), 256, 0, stream>>>(W1, Wm, bm, Wbf, bias);
  transpose_in<<<dim3(64, 8, 4), dim3(32, 8), 0, stream>>>(desc0, desc1, Dm, Hin, XMl);

  for (int l = 0; l < NL; l++) {
    const bf16* wl = Wbf + (size_t)l * 1310720;
    const float* bl = bias + l * 2304;
    int cross = l & 1;
    // fused QKV (Q pre-scaled by log2e/8)
    gemm3<0, 128><<<dim3(64, 6), 256, 0, stream>>>(Hin, 512, XMl, 512,
        wl, wl + 196608, 256, bl, nullptr,
        Qh, Ql, Kh, Kl, Vth, Vtl, nullptr);
    // split-KV attention + combine (combine writes O into Hin/XMl msg-half)
    attn3s<<<dim3(16, 16, 2), 512, 0, stream>>>(Qh, Ql, Kh, Kl, Vth, Vtl,
                                                Pacc, Ml, cross);
    attn_combine<<<2048, 256, 0, stream>>>(Pacc, Ml, Hin, XMl);
    // MLP1 (merge folded in: A = [x | O], W1eff) + BN + ReLU
    gemm3<3, 128><<<dim3(64, 4), 256, 0, stream>>>(Hin, 512, XMl, 512,
        wl + 524288, wl + 786432, 512, bl + 1024, bl + 1536,
        Hbh, Hbl, nullptr, nullptr, nullptr, nullptr, nullptr);
    // MLP2 + residual
    gemm3<4, 64><<<dim3(64, 4), 256, 0, stream>>>(Hbh, 512, Hbl, 512,
        wl + 1048576, wl + 1179648, 512, bl + 2048, nullptr,
        Hin, XMl, nullptr, nullptr, nullptr, nullptr, Dm);
  }
  transpose_out<<<dim3(64, 8, 4), dim3(32, 8), 0, stream>>>(Dm, out);
}

// Round 14
// 1660.506 us; speedup vs baseline: 1.5558x; 1.0449x over previous
//
#include <hip/hip_runtime.h>

typedef unsigned short bf16;
typedef __attribute__((ext_vector_type(8))) short bf16x8;
typedef __attribute__((ext_vector_type(4))) float f32x4;
typedef unsigned short u16x4 __attribute__((ext_vector_type(4)));

#define DEVFN static __device__ __forceinline__

#define NL 12

#define VMW(N) asm volatile("s_waitcnt vmcnt(" #N ")" ::: "memory")
#define RBAR() asm volatile("s_barrier" ::: "memory")
#define SCHB() __builtin_amdgcn_sched_barrier(0)

DEVFN unsigned short f2bf(float f) {
  union { float f; unsigned u; } v; v.f = f;
  unsigned u = v.u;
  unsigned r = (u + 0x7fffu + ((u >> 16) & 1u)) >> 16;  // RNE
  return (unsigned short)r;
}
DEVFN float bf2f(unsigned short h) {
  union { unsigned u; float f; } v; v.u = ((unsigned)h) << 16; return v.f;
}
// truncation hi/lo split: 4 ALU ops, pair error ~2^-18
DEVFN void tsplit(float v, unsigned short& h, unsigned short& l) {
  union { float f; unsigned u; } a; a.f = v;
  h = (unsigned short)(a.u >> 16);
  union { float f; unsigned u; } b; b.u = a.u & 0xffff0000u;
  union { float f; unsigned u; } c; c.f = v - b.f;
  l = (unsigned short)(c.u >> 16);
}
// async global->LDS, 16B per lane; dest = wave-uniform base + lane*16
DEVFN void gll16(const bf16* g, bf16* l) {
  __builtin_amdgcn_global_load_lds(
      (const __attribute__((address_space(1))) unsigned int*)g,
      (__attribute__((address_space(3))) unsigned int*)l, 16, 0, 0);
}

#define MFMA_BF16(a, b, c) __builtin_amdgcn_mfma_f32_16x16x32_bf16((a), (b), (c), 0, 0, 0)

// ---------------------------------------------------------------------------
// Weight prep v2: one thread per WEIGHT ELEMENT (hi+lo computed together).
// Wq/bq folded with Cs = log2(e)/8. Per-layer bf16 block (1310720):
//   [0,196608) Wqkv hi | [196608,393216) Wqkv lo | [393216,524288) unused
//   [524288,786432) W1eff hi | [786432,1048576) W1eff lo
//   [1048576,1179648) W2 hi | [1179648,1310720) W2 lo
// W1eff cols 256:512 are overwritten by prep_fold with E = W1b·Wm (permuted).
// f32 bias block (2304): bqkv[768] | bm[256] | geff[512] | beff[512] | b2[256]
// Work items/layer: 196608 (Wqkv) + 262144 (W1) + 131072 (W2) + 2304 = 592128.
// ---------------------------------------------------------------------------
__global__ void prep_weights(const float* __restrict__ Wq, const float* __restrict__ bq,
                             const float* __restrict__ Wk, const float* __restrict__ bk,
                             const float* __restrict__ Wv, const float* __restrict__ bv,
                             const float* __restrict__ Wm, const float* __restrict__ bm,
                             const float* __restrict__ W1, const float* __restrict__ b1,
                             const float* __restrict__ gm, const float* __restrict__ bt,
                             const float* __restrict__ W2, const float* __restrict__ b2,
                             bf16* __restrict__ Wbf, float* __restrict__ bias)
{
  int l = blockIdx.y;
  bf16* wl = Wbf + (size_t)l * 1310720;
  float* bl = bias + l * 2304;
  int j = blockIdx.x * blockDim.x + threadIdx.x;
  if (j >= 592128) return;
  const float INV = 1.0f / sqrtf(1.0f + 1e-5f);
  const float Cs = 0.18033688011112042f;  // log2(e)/8

  float w;
  size_t oh, ol;
  if (j < 196608) {                           // Wqkv, permuted rows
    int t = j >> 16;
    int p = (j >> 8) & 255;
    int k = j & 255;
    int c = ((p & 63) << 2) | (p >> 6);       // p = h*64+i -> c = i*4+h
    const float* W = (t == 0) ? Wq : (t == 1) ? Wk : Wv;
    w = W[(size_t)l * 65536 + c * 256 + k];
    if (t == 0) w *= Cs;
    oh = j; ol = j + 196608;
  } else if (j < 458752) {                    // W1 (msg-cols overwritten by fold)
    int j2 = j - 196608;
    w = W1[(size_t)l * 262144 + j2];
    oh = 524288 + j2; ol = 786432 + j2;
  } else if (j < 589824) {                    // W2
    int j3 = j - 458752;
    w = W2[(size_t)l * 131072 + j3];
    oh = 1048576 + j3; ol = 1179648 + j3;
  } else {                                    // bias
    int b = j - 589824;
    if (b < 768) {
      int t = b >> 8, p = b & 255;
      int c = ((p & 63) << 2) | (p >> 6);
      const float* bsrc = (t == 0) ? bq : (t == 1) ? bk : bv;
      bl[b] = bsrc[l * 256 + c] * ((t == 0) ? Cs : 1.0f);
    } else if (b < 1024) {
      bl[b] = bm[l * 256 + (b - 768)];
    } else if (b < 1536) {
      bl[b] = gm[l * 512 + (b - 1024)] * INV;
    } else if (b < 2048) {
      int o = b - 1536;
      bl[b] = gm[l * 512 + o] * INV * b1[l * 512 + o] + bt[l * 512 + o];
    } else {
      bl[b] = b2[l * 256 + (b - 2048)];
    }
    return;
  }
  unsigned short hi = f2bf(w);
  wl[oh] = hi;
  wl[ol] = f2bf(w - bf2f(hi));
}

// ---------------------------------------------------------------------------
// Merge-GEMM fold v2 (coalesced): E'[r][k] = sum_oc W1b[r][oc]*Wm[oc][k]
// (plain column k -> coalesced Wm reads, Wm is L2-resident per layer), stored
// at permuted col p = ((k&3)<<6)|(k>>2) so that perm(p) = k matches the
// head-major O layout. beff[r] += geff[r]*(W1b·bm)[r].
// grid (64, 12), 256 threads; block = 8 rows x 256 k. Runs after prep_weights
// (stream-ordered; beff re-initialized each call -> deterministic replay).
// ---------------------------------------------------------------------------
__global__ void prep_fold(const float* __restrict__ W1, const float* __restrict__ Wm,
                          const float* __restrict__ bm,
                          bf16* __restrict__ Wbf, float* __restrict__ bias)
{
  int l = blockIdx.y;
  int r0 = blockIdx.x * 8;
  int k = threadIdx.x;
  __shared__ float w1b[8][256];
  for (int j = threadIdx.x; j < 2048; j += 256)
    w1b[j >> 8][j & 255] = W1[(size_t)l * 262144 + (r0 + (j >> 8)) * 512 + 256 + (j & 255)];
  __syncthreads();
  float acc[8] = {0.f, 0.f, 0.f, 0.f, 0.f, 0.f, 0.f, 0.f};
  const float* wmrow = Wm + (size_t)l * 65536 + k;
  for (int oc = 0; oc < 256; oc++) {
    float wv = wmrow[oc * 256];               // coalesced across threads
    #pragma unroll
    for (int j = 0; j < 8; j++) acc[j] += w1b[j][oc] * wv;  // LDS broadcast
  }
  int p = ((k & 3) << 6) | (k >> 2);          // inv-perm: perm(p) == k
  bf16* wl = Wbf + (size_t)l * 1310720;
  #pragma unroll
  for (int j = 0; j < 8; j++) {
    unsigned short hi = f2bf(acc[j]);
    wl[524288 + (size_t)(r0 + j) * 512 + 256 + p] = hi;
    wl[786432 + (size_t)(r0 + j) * 512 + 256 + p] = f2bf(acc[j] - bf2f(hi));
  }
  if (threadIdx.x < 8) {
    int j = threadIdx.x;
    float d = 0.f;
    for (int oc = 0; oc < 256; oc++) d += w1b[j][oc] * bm[l * 256 + oc];
    float ge = bias[l * 2304 + 1024 + r0 + j];
    bias[l * 2304 + 1536 + r0 + j] += ge * d;   // unique writer per row
  }
}

// ---------------------------------------------------------------------------
__global__ void transpose_in(const float* __restrict__ s0, const float* __restrict__ s1,
                             float* __restrict__ Dm, bf16* __restrict__ Hin,
                             bf16* __restrict__ XMl)
{
  __shared__ float t[32][33];
  int db = blockIdx.z;
  int dsc = db >> 1, bi = db & 1;
  const float* src = dsc ? s1 : s0;
  int n0 = blockIdx.x * 32, d0 = blockIdx.y * 32;
  int tx = threadIdx.x, ty = threadIdx.y;
  #pragma unroll
  for (int i = 0; i < 32; i += 8)
    t[ty + i][tx] = src[(size_t)(bi * 256 + d0 + ty + i) * 2048 + n0 + tx];
  __syncthreads();
  #pragma unroll
  for (int i = 0; i < 32; i += 8) {
    size_t xi = (size_t)db * 2048 + n0 + ty + i;
    float v = t[tx][ty + i];
    Dm[xi * 256 + d0 + tx] = v;
    unsigned short hi, lo;
    tsplit(v, hi, lo);
    Hin[xi * 512 + d0 + tx] = hi;
    XMl[xi * 512 + d0 + tx] = lo;
  }
}

__global__ void transpose_out(const float* __restrict__ Dm, float* __restrict__ out)
{
  __shared__ float t[32][33];
  int db = blockIdx.z;
  int n0 = blockIdx.x * 32, d0 = blockIdx.y * 32;
  int tx = threadIdx.x, ty = threadIdx.y;
  #pragma unroll
  for (int i = 0; i < 32; i += 8)
    t[ty + i][tx] = Dm[((size_t)db * 2048 + n0 + ty + i) * 256 + d0 + tx];
  __syncthreads();
  #pragma unroll
  for (int i = 0; i < 32; i += 8)
    out[(size_t)(db * 256 + d0 + ty + i) * 2048 + n0 + tx] = t[tx][ty + i];
}

// ---------------------------------------------------------------------------
// 3-term split GEMM (round-12 structure): tile 128xNT, BK=32, 4 waves,
// double-buffered global_load_lds, counted vmcnt + raw bars, sigma-swizzle
// gsw2 (coalesced staging quads + conflict-free reads).
// ---------------------------------------------------------------------------
DEVFN int gsw2(int row, int g) { return row * 32 + (((g ^ (row >> 1)) & 3) << 3); }

template<int EPI, int NT>
__global__ __launch_bounds__(256, (NT == 128) ? 2 : 3) void gemm3(
    const bf16* __restrict__ Ah, int lda,
    const bf16* __restrict__ Al, int ldal,
    const bf16* __restrict__ Wh, const bf16* __restrict__ Wl, int K,
    const float* __restrict__ b0, const float* __restrict__ b1,
    bf16* __restrict__ o0, bf16* __restrict__ o1,
    bf16* __restrict__ o2, bf16* __restrict__ o3,
    bf16* __restrict__ o4, bf16* __restrict__ o5,
    float* __restrict__ of)
{
  constexpr int NFR = NT / 32;
  __shared__ bf16 AsH[2][4096];
  __shared__ bf16 AsL[2][4096];
  __shared__ bf16 BsH[2][NT * 32];
  __shared__ bf16 BsL[2][NT * 32];
  int tid = threadIdx.x, lane = tid & 63, wid = tid >> 6;
  int wr = wid >> 1, wc = wid & 1;
  int m0 = blockIdx.x * 128, n0 = blockIdx.y * NT;

  int lrow = lane >> 2;
  int g4 = (((lane & 3) ^ (lane >> 3)) & 3) << 3;
  const bf16* A0h = Ah + (size_t)(m0 + wid * 16 + lrow) * lda + g4;
  const bf16* A0l = Al + (size_t)(m0 + wid * 16 + lrow) * ldal + g4;
  const bf16* B0h = Wh + (size_t)(n0 + wid * 16 + lrow) * K + g4;
  const bf16* B0l = Wl + (size_t)(n0 + wid * 16 + lrow) * K + g4;
  size_t a64h = (size_t)64 * lda, a64l = (size_t)64 * ldal, b64 = (size_t)64 * K;

  auto issue = [&](int k0, int b) {
    gll16(A0h + k0, &AsH[b][wid * 512]);
    gll16(A0h + a64h + k0, &AsH[b][2048 + wid * 512]);
    gll16(A0l + k0, &AsL[b][wid * 512]);
    gll16(A0l + a64l + k0, &AsL[b][2048 + wid * 512]);
    gll16(B0h + k0, &BsH[b][wid * 512]);
    gll16(B0l + k0, &BsL[b][wid * 512]);
    if constexpr (NT == 128) {
      gll16(B0h + b64 + k0, &BsH[b][2048 + wid * 512]);
      gll16(B0l + b64 + k0, &BsL[b][2048 + wid * 512]);
    }
  };

  f32x4 zero = {0.f, 0.f, 0.f, 0.f};
  f32x4 acc[4][NFR];
  #pragma unroll
  for (int i = 0; i < 4; i++)
    #pragma unroll
    for (int j = 0; j < NFR; j++) acc[i][j] = zero;

  int fr = lane & 15, g = lane >> 4;
  int cb = wc * (NT / 2);
  int nk = K >> 5;

  issue(0, 0);
  for (int ks = 0; ks < nk; ks++) {
    int cur = ks & 1;
    if (ks + 1 < nk) {
      issue((ks + 1) << 5, cur ^ 1);
      if constexpr (NT == 128) VMW(8); else VMW(6);
    } else {
      VMW(0);
    }
    RBAR(); SCHB();
    bf16x8 afh[4], afl[4], bfh[NFR], bfl[NFR];
    #pragma unroll
    for (int i = 0; i < 4; i++) {
      afh[i] = *(const bf16x8*)(&AsH[cur][gsw2(wr * 64 + i * 16 + fr, g)]);
      afl[i] = *(const bf16x8*)(&AsL[cur][gsw2(wr * 64 + i * 16 + fr, g)]);
    }
    #pragma unroll
    for (int i = 0; i < NFR; i++) {
      bfh[i] = *(const bf16x8*)(&BsH[cur][gsw2(cb + i * 16 + fr, g)]);
      bfl[i] = *(const bf16x8*)(&BsL[cur][gsw2(cb + i * 16 + fr, g)]);
    }
    #pragma unroll
    for (int mi = 0; mi < 4; mi++)
      #pragma unroll
      for (int ni = 0; ni < NFR; ni++) {
        acc[mi][ni] = MFMA_BF16(afh[mi], bfh[ni], acc[mi][ni]);
        acc[mi][ni] = MFMA_BF16(afl[mi], bfh[ni], acc[mi][ni]);
        acc[mi][ni] = MFMA_BF16(afh[mi], bfl[ni], acc[mi][ni]);
      }
    RBAR();
  }

  #pragma unroll
  for (int mi = 0; mi < 4; mi++) {
    #pragma unroll
    for (int ni = 0; ni < NFR; ni++) {
      int mrow = m0 + wr * 64 + mi * 16 + ((lane >> 4) << 2);
      int ocol = n0 + cb + ni * 16 + fr;
      if constexpr (EPI == 0) {          // fused QKV
        float bb = b0[ocol];
        if (ocol < 512) {
          bf16* Dh = (ocol < 256) ? o0 : o2;
          bf16* Dl = (ocol < 256) ? o1 : o3;
          int oo = ocol & 255;
          #pragma unroll
          for (int r = 0; r < 4; r++) {
            unsigned short hi, lo;
            tsplit(acc[mi][ni][r] + bb, hi, lo);
            Dh[(size_t)(mrow + r) * 256 + oo] = hi;
            Dl[(size_t)(mrow + r) * 256 + oo] = lo;
          }
        } else {
          int c = ocol - 512;
          int dbi = mrow >> 11, nn = mrow & 2047;
          u16x4 ph, pl;
          #pragma unroll
          for (int r = 0; r < 4; r++) {
            unsigned short hi, lo;
            tsplit(acc[mi][ni][r] + bb, hi, lo);
            ph[r] = hi; pl[r] = lo;
          }
          *(u16x4*)(&o4[((size_t)dbi * 256 + c) * 2048 + nn]) = ph;
          *(u16x4*)(&o5[((size_t)dbi * 256 + c) * 2048 + nn]) = pl;
        }
      } else if constexpr (EPI == 3) {   // BN+ReLU hi+lo
        float ge = b0[ocol], be = b1[ocol];
        #pragma unroll
        for (int r = 0; r < 4; r++) {
          unsigned short hi, lo;
          tsplit(fmaxf(ge * acc[mi][ni][r] + be, 0.f), hi, lo);
          o0[(size_t)(mrow + r) * 512 + ocol] = hi;
          o1[(size_t)(mrow + r) * 512 + ocol] = lo;
        }
      } else {                           // EPI 4: residual
        float bb = b0[ocol];
        #pragma unroll
        for (int r = 0; r < 4; r++) {
          size_t ix = (size_t)(mrow + r) * 256 + ocol;
          float d = of[ix] + acc[mi][ni][r] + bb;
          of[ix] = d;
          unsigned short hi, lo;
          tsplit(d, hi, lo);
          o0[(size_t)(mrow + r) * 512 + ocol] = hi;
          o1[(size_t)(mrow + r) * 512 + ocol] = lo;
        }
      }
    }
  }
}

// ---------------------------------------------------------------------------
// Flash attention (round-13 structure): split-KV, 8 waves x 16 rows, 3-term
// QK^T/PV, 3-phase pipeline, cheap defer-max check.
// ---------------------------------------------------------------------------
DEVFN int swz(int row, int col) { return row * 64 + (col ^ ((row & 7) << 3)); }

__global__ __launch_bounds__(512, 4) void attn3s(
    const bf16* __restrict__ Qh, const bf16* __restrict__ Ql,
    const bf16* __restrict__ Kh, const bf16* __restrict__ Kl,
    const bf16* __restrict__ Vth, const bf16* __restrict__ Vtl,
    float* __restrict__ Pacc, float* __restrict__ Ml, int cross)
{
  __shared__ bf16 Ksh[64 * 64];
  __shared__ bf16 Ksl[64 * 64];
  __shared__ bf16 Vsh[64 * 64];
  __shared__ bf16 Vsl[64 * 64];
  __shared__ bf16 Psh[8][1024];
  __shared__ bf16 Psl[8][1024];
  int tid = threadIdx.x, lane = tid & 63, w = tid >> 6;
  int inst = blockIdx.y;
  int half = blockIdx.z;
  int db = inst >> 2, hd = inst & 3;
  int dsc = db >> 1, bi = db & 1;
  int sdb = (cross ? (1 - dsc) : dsc) * 2 + bi;
  size_t xq = (size_t)db * 2048;
  size_t xs = (size_t)sdb * 2048 + half * 1024;
  int n0 = blockIdx.x * 128;

  int fr = lane & 15, kof = (lane >> 4) << 3;

  bf16x8 aqh[2], aql[2];
  #pragma unroll
  for (int kf = 0; kf < 2; kf++) {
    size_t g = (xq + n0 + w * 16 + fr) * 256 + hd * 64 + kf * 32 + kof;
    aqh[kf] = *(const bf16x8*)(Qh + g);
    aql[kf] = *(const bf16x8*)(Ql + g);
  }

  f32x4 zero = {0.f, 0.f, 0.f, 0.f};
  f32x4 oacc[4];
  #pragma unroll
  for (int ni = 0; ni < 4; ni++) oacc[ni] = zero;
  float mrun[4], lrun[4];
  #pragma unroll
  for (int r = 0; r < 4; r++) { mrun[r] = -3.0e38f; lrun[r] = 0.f; }

  bf16x8 vone;
  #pragma unroll
  for (int i = 0; i < 8; i++) vone[i] = (short)0x3F80;  // bf16 1.0

  int lrow = lane >> 3;
  int g8 = ((lane & 7) ^ (lrow & 7)) << 3;
  int krow = w * 8 + lrow;
  const bf16* Ksrc_h = Kh + (xs + krow) * 256 + hd * 64 + g8;
  const bf16* Ksrc_l = Kl + (xs + krow) * 256 + hd * 64 + g8;
  const bf16* Vsrc_h = Vth + ((size_t)sdb * 256 + hd * 64 + krow) * 2048 + half * 1024 + g8;
  const bf16* Vsrc_l = Vtl + ((size_t)sdb * 256 + hd * 64 + krow) * 2048 + half * 1024 + g8;
  bf16* LKh = Ksh + w * 512;
  bf16* LKl = Ksl + w * 512;
  bf16* LVh = Vsh + w * 512;
  bf16* LVl = Vsl + w * 512;

  gll16(Ksrc_h, LKh);
  gll16(Ksrc_l, LKl);
  gll16(Vsrc_h, LVh);
  gll16(Vsrc_l, LVl);

  for (int t = 0; t < 16; t++) {
    VMW(4);            // K(t) landed; V(t) loads stay in flight
    RBAR(); SCHB();

    // ---- QK^T (3-term) ----
    f32x4 sacc[4];
    #pragma unroll
    for (int ni = 0; ni < 4; ni++) sacc[ni] = zero;
    #pragma unroll
    for (int kf = 0; kf < 2; kf++) {
      #pragma unroll
      for (int ni = 0; ni < 4; ni++) {
        bf16x8 bkh = *(const bf16x8*)(&Ksh[swz(ni * 16 + fr, kf * 32 + kof)]);
        bf16x8 bkl = *(const bf16x8*)(&Ksl[swz(ni * 16 + fr, kf * 32 + kof)]);
        sacc[ni] = MFMA_BF16(aqh[kf], bkh, sacc[ni]);
        sacc[ni] = MFMA_BF16(aql[kf], bkh, sacc[ni]);
        sacc[ni] = MFMA_BF16(aqh[kf], bkl, sacc[ni]);
      }
    }

    // ---- cheap defer-max check (full reduce only when needed) ----
    float tml[4];
    bool need = false;
    #pragma unroll
    for (int r = 0; r < 4; r++) {
      tml[r] = fmaxf(fmaxf(sacc[0][r], sacc[1][r]), fmaxf(sacc[2][r], sacc[3][r]));
      need = need || (tml[r] > mrun[r] + 8.0f);
    }
    if (__ballot(need)) {
      #pragma unroll
      for (int r = 0; r < 4; r++) {
        float tm = tml[r];
        tm = fmaxf(tm, __shfl_xor(tm, 1));
        tm = fmaxf(tm, __shfl_xor(tm, 2));
        tm = fmaxf(tm, __shfl_xor(tm, 4));
        tm = fmaxf(tm, __shfl_xor(tm, 8));
        float mn = fmaxf(mrun[r], tm);
        float s = exp2f(mrun[r] - mn);
        mrun[r] = mn;
        lrun[r] *= s;
        #pragma unroll
        for (int ni = 0; ni < 4; ni++) oacc[ni][r] *= s;
      }
    }
    #pragma unroll
    for (int r = 0; r < 4; r++)
      #pragma unroll
      for (int ni = 0; ni < 4; ni++)
        sacc[ni][r] = exp2f(sacc[ni][r] - mrun[r]);

    VMW(0);            // V(t) landed
    RBAR(); SCHB();

    if (t + 1 < 16) {  // K(t+1) flies under P-store + PV
      gll16(Ksrc_h + (size_t)(t + 1) * 16384, LKh);
      gll16(Ksrc_l + (size_t)(t + 1) * 16384, LKl);
    }

    // ---- P -> LDS (own wave region) ----
    bf16* Pwh = &Psh[w][0];
    bf16* Pwl = &Psl[w][0];
    #pragma unroll
    for (int ni = 0; ni < 4; ni++) {
      int col = ni * 16 + fr;
      #pragma unroll
      for (int r = 0; r < 4; r++) {
        int row = ((lane >> 4) << 2) + r;
        unsigned short hi, lo;
        tsplit(sacc[ni][r], hi, lo);
        Pwh[swz(row, col)] = hi;
        Pwl[swz(row, col)] = lo;
      }
    }

    // ---- PV (3-term) + row-sum via ones-MFMA ----
    f32x4 racc = zero;
    #pragma unroll
    for (int kf = 0; kf < 2; kf++) {
      bf16x8 pah = *(const bf16x8*)(&Pwh[swz(fr, kf * 32 + kof)]);
      bf16x8 pal = *(const bf16x8*)(&Pwl[swz(fr, kf * 32 + kof)]);
      #pragma unroll
      for (int ni = 0; ni < 4; ni++) {
        bf16x8 bvh = *(const bf16x8*)(&Vsh[swz(ni * 16 + fr, kf * 32 + kof)]);
        bf16x8 bvl = *(const bf16x8*)(&Vsl[swz(ni * 16 + fr, kf * 32 + kof)]);
        oacc[ni] = MFMA_BF16(pah, bvh, oacc[ni]);
        oacc[ni] = MFMA_BF16(pal, bvh, oacc[ni]);
        oacc[ni] = MFMA_BF16(pah, bvl, oacc[ni]);
      }
      racc = MFMA_BF16(pah, vone, racc);
      racc = MFMA_BF16(pal, vone, racc);
    }
    #pragma unroll
    for (int r = 0; r < 4; r++)
      lrun[r] += racc[r];

    RBAR();
    if (t + 1 < 16) {  // V(t+1) flies under next QK^T + softmax
      gll16(Vsrc_h + (t + 1) * 64, LVh);
      gll16(Vsrc_l + (t + 1) * 64, LVl);
    }
  }

  float* Pb = Pacc + (size_t)half * 8192 * 256;
  #pragma unroll
  for (int r = 0; r < 4; r++) {
    int nrow = n0 + w * 16 + ((lane >> 4) << 2) + r;
    size_t row = xq + nrow;
    #pragma unroll
    for (int ni = 0; ni < 4; ni++)
      Pb[row * 256 + hd * 64 + ni * 16 + fr] = oacc[ni][r];
    if (fr == 0) {
      float* mp = Ml + ((row * 4 + hd) << 2) + half * 2;
      mp[0] = mrun[r];
      mp[1] = lrun[r];
    }
  }
}

// ---------------------------------------------------------------------------
// Combine the two KV halves; writes O directly into Hin/XMl cols 256:512.
// ---------------------------------------------------------------------------
__global__ __launch_bounds__(256) void attn_combine(
    const float* __restrict__ Pacc, const float* __restrict__ Ml,
    bf16* __restrict__ Hin, bf16* __restrict__ XMl)
{
  int tid = threadIdx.x, lane = tid & 63, w = tid >> 6;
  size_t row = (size_t)blockIdx.x * 4 + w;
  int hd = lane >> 4;
  int c0 = lane * 4;
  const float* mp = Ml + ((row * 4 + hd) << 2);
  float ma = mp[0], la = mp[1], mb = mp[2], lb = mp[3];
  float m = fmaxf(ma, mb);
  float wa = exp2f(ma - m), wb = exp2f(mb - m);
  float inv = 1.0f / (la * wa + lb * wb);
  wa *= inv; wb *= inv;
  f32x4 pa = *(const f32x4*)(Pacc + row * 256 + c0);
  f32x4 pb = *(const f32x4*)(Pacc + (size_t)8192 * 256 + row * 256 + c0);
  u16x4 vh, vl;
  #pragma unroll
  for (int r = 0; r < 4; r++) {
    unsigned short hi, lo;
    tsplit(pa[r] * wa + pb[r] * wb, hi, lo);
    vh[r] = hi; vl[r] = lo;
  }
  *(u16x4*)(Hin + row * 512 + 256 + c0) = vh;
  *(u16x4*)(XMl + row * 512 + 256 + c0) = vl;
}

// ---------------------------------------------------------------------------
extern "C" void kernel_launch(void* const* d_in, const int* in_sizes, int n_in,
                              void* d_out, int out_size, void* d_ws, size_t ws_size,
                              hipStream_t stream)
{
  (void)in_sizes; (void)n_in; (void)out_size; (void)ws_size;
  const float* desc0 = (const float*)d_in[0];
  const float* desc1 = (const float*)d_in[1];
  const float* Wq = (const float*)d_in[2];
  const float* bq = (const float*)d_in[3];
  const float* Wk = (const float*)d_in[4];
  const float* bk = (const float*)d_in[5];
  const float* Wv = (const float*)d_in[6];
  const float* bv = (const float*)d_in[7];
  const float* Wm = (const float*)d_in[8];
  const float* bm = (const float*)d_in[9];
  const float* W1 = (const float*)d_in[10];
  const float* b1 = (const float*)d_in[11];
  const float* gm = (const float*)d_in[12];
  const float* bt = (const float*)d_in[13];
  const float* W2 = (const float*)d_in[14];
  const float* b2 = (const float*)d_in[15];
  float* out = (float*)d_out;

  char* ws = (char*)d_ws;
  bf16*  Wbf  = (bf16*)(ws + 0);            //  31,457,280
  float* bias = (float*)(ws + 31457280);    //     110,592
  float* Dm   = (float*)(ws + 31567872);    //  16,777,216  fp32 master [xi,256]
  bf16*  Hin  = (bf16*)(ws + 48345088);     //  16,777,216  [xi,512] = xh | O_h
  bf16*  XMl  = (bf16*)(ws + 65122304);     //  16,777,216  [xi,512] = xl | O_l
  bf16*  Qh   = (bf16*)(ws + 81899520);     //   8,388,608
  bf16*  Ql   = (bf16*)(ws + 90288128);     //   8,388,608
  bf16*  Kh   = (bf16*)(ws + 98676736);     //   8,388,608
  bf16*  Kl   = (bf16*)(ws + 107065344);    //   8,388,608
  bf16*  Vth  = (bf16*)(ws + 115453952);    //   8,388,608  [db,256,2048]
  bf16*  Vtl  = (bf16*)(ws + 123842560);    //   8,388,608
  float* Pacc = (float*)(ws + 132231168);   //  16,777,216  [2][8192][256] fp32
  float* Ml   = (float*)(ws + 149008384);   //     524,288  [8192][4][4]
  // end: 149,532,672
  bf16*  Hbh  = Qh;                         // alias Qh+Ql (disjoint in time)
  bf16*  Hbl  = Kh;                         // alias Kh+Kl

  prep_weights<<<dim3(2313, 12), 256, 0, stream>>>(Wq, bq, Wk, bk, Wv, bv, Wm, bm,
                                                   W1, b1, gm, bt, W2, b2, Wbf, bias);
  prep_fold<<<dim3(64, 12), 256, 0, stream>>>(W1, Wm, bm, Wbf, bias);
  transpose_in<<<dim3(64, 8, 4), dim3(32, 8), 0, stream>>>(desc0, desc1, Dm, Hin, XMl);

  for (int l = 0; l < NL; l++) {
    const bf16* wl = Wbf + (size_t)l * 1310720;
    const float* bl = bias + l * 2304;
    int cross = l & 1;
    // fused QKV (Q pre-scaled by log2e/8)
    gemm3<0, 128><<<dim3(64, 6), 256, 0, stream>>>(Hin, 512, XMl, 512,
        wl, wl + 196608, 256, bl, nullptr,
        Qh, Ql, Kh, Kl, Vth, Vtl, nullptr);
    // split-KV attention + combine (combine writes O into Hin/XMl msg-half)
    attn3s<<<dim3(16, 16, 2), 512, 0, stream>>>(Qh, Ql, Kh, Kl, Vth, Vtl,
                                                Pacc, Ml, cross);
    attn_combine<<<2048, 256, 0, stream>>>(Pacc, Ml, Hin, XMl);
    // MLP1 (merge folded in: A = [x | O], W1eff) + BN + ReLU
    gemm3<3, 128><<<dim3(64, 4), 256, 0, stream>>>(Hin, 512, XMl, 512,
        wl + 524288, wl + 786432, 512, bl + 1024, bl + 1536,
        Hbh, Hbl, nullptr, nullptr, nullptr, nullptr, nullptr);
    // MLP2 + residual
    gemm3<4, 64><<<dim3(64, 4), 256, 0, stream>>>(Hbh, 512, Hbl, 512,
        wl + 1048576, wl + 1179648, 512, bl + 2048, nullptr,
        Hin, XMl, nullptr, nullptr, nullptr, nullptr, Dm);
  }
  transpose_out<<<dim3(64, 8, 4), dim3(32, 8), 0, stream>>>(Dm, out);
}

// Round 15
// 1578.104 us; speedup vs baseline: 1.6370x; 1.0522x over previous
//
#include <hip/hip_runtime.h>

typedef unsigned short bf16;
typedef __attribute__((ext_vector_type(8))) short bf16x8;
typedef __attribute__((ext_vector_type(4))) float f32x4;
typedef unsigned short u16x4 __attribute__((ext_vector_type(4)));

#define DEVFN static __device__ __forceinline__

#define NL 12

#define VMW(N) asm volatile("s_waitcnt vmcnt(" #N ")" ::: "memory")
#define RBAR() asm volatile("s_barrier" ::: "memory")
#define SCHB() __builtin_amdgcn_sched_barrier(0)

DEVFN unsigned short f2bf(float f) {
  union { float f; unsigned u; } v; v.f = f;
  unsigned u = v.u;
  unsigned r = (u + 0x7fffu + ((u >> 16) & 1u)) >> 16;  // RNE
  return (unsigned short)r;
}
DEVFN float bf2f(unsigned short h) {
  union { unsigned u; float f; } v; v.u = ((unsigned)h) << 16; return v.f;
}
// truncation hi/lo split: 4 ALU ops, pair error ~2^-18
DEVFN void tsplit(float v, unsigned short& h, unsigned short& l) {
  union { float f; unsigned u; } a; a.f = v;
  h = (unsigned short)(a.u >> 16);
  union { float f; unsigned u; } b; b.u = a.u & 0xffff0000u;
  union { float f; unsigned u; } c; c.f = v - b.f;
  l = (unsigned short)(c.u >> 16);
}
// async global->LDS, 16B per lane; dest = wave-uniform base + lane*16
DEVFN void gll16(const bf16* g, bf16* l) {
  __builtin_amdgcn_global_load_lds(
      (const __attribute__((address_space(1))) unsigned int*)g,
      (__attribute__((address_space(3))) unsigned int*)l, 16, 0, 0);
}

#define MFMA_BF16(a, b, c) __builtin_amdgcn_mfma_f32_16x16x32_bf16((a), (b), (c), 0, 0, 0)

// ---------------------------------------------------------------------------
// Weight prep v2: one thread per WEIGHT ELEMENT (hi+lo computed together).
// Wq/bq folded with Cs = log2(e)/8. Per-layer bf16 block (1310720):
//   [0,196608) Wqkv hi | [196608,393216) Wqkv lo | [393216,524288) unused
//   [524288,786432) W1eff hi | [786432,1048576) W1eff lo
//   [1048576,1179648) W2 hi | [1179648,1310720) W2 lo
// W1eff cols 256:512 are overwritten by prep_fold with E = W1b·Wm (permuted).
// f32 bias block (2304): bqkv[768] | bm[256] | geff[512] | beff[512] | b2[256]
// ---------------------------------------------------------------------------
__global__ void prep_weights(const float* __restrict__ Wq, const float* __restrict__ bq,
                             const float* __restrict__ Wk, const float* __restrict__ bk,
                             const float* __restrict__ Wv, const float* __restrict__ bv,
                             const float* __restrict__ Wm, const float* __restrict__ bm,
                             const float* __restrict__ W1, const float* __restrict__ b1,
                             const float* __restrict__ gm, const float* __restrict__ bt,
                             const float* __restrict__ W2, const float* __restrict__ b2,
                             bf16* __restrict__ Wbf, float* __restrict__ bias)
{
  int l = blockIdx.y;
  bf16* wl = Wbf + (size_t)l * 1310720;
  float* bl = bias + l * 2304;
  int j = blockIdx.x * blockDim.x + threadIdx.x;
  if (j >= 592128) return;
  const float INV = 1.0f / sqrtf(1.0f + 1e-5f);
  const float Cs = 0.18033688011112042f;  // log2(e)/8

  float w;
  size_t oh, ol;
  if (j < 196608) {                           // Wqkv, permuted rows
    int t = j >> 16;
    int p = (j >> 8) & 255;
    int k = j & 255;
    int c = ((p & 63) << 2) | (p >> 6);       // p = h*64+i -> c = i*4+h
    const float* W = (t == 0) ? Wq : (t == 1) ? Wk : Wv;
    w = W[(size_t)l * 65536 + c * 256 + k];
    if (t == 0) w *= Cs;
    oh = j; ol = j + 196608;
  } else if (j < 458752) {                    // W1 (msg-cols overwritten by fold)
    int j2 = j - 196608;
    w = W1[(size_t)l * 262144 + j2];
    oh = 524288 + j2; ol = 786432 + j2;
  } else if (j < 589824) {                    // W2
    int j3 = j - 458752;
    w = W2[(size_t)l * 131072 + j3];
    oh = 1048576 + j3; ol = 1179648 + j3;
  } else {                                    // bias
    int b = j - 589824;
    if (b < 768) {
      int t = b >> 8, p = b & 255;
      int c = ((p & 63) << 2) | (p >> 6);
      const float* bsrc = (t == 0) ? bq : (t == 1) ? bk : bv;
      bl[b] = bsrc[l * 256 + c] * ((t == 0) ? Cs : 1.0f);
    } else if (b < 1024) {
      bl[b] = bm[l * 256 + (b - 768)];
    } else if (b < 1536) {
      bl[b] = gm[l * 512 + (b - 1024)] * INV;
    } else if (b < 2048) {
      int o = b - 1536;
      bl[b] = gm[l * 512 + o] * INV * b1[l * 512 + o] + bt[l * 512 + o];
    } else {
      bl[b] = b2[l * 256 + (b - 2048)];
    }
    return;
  }
  unsigned short hi = f2bf(w);
  wl[oh] = hi;
  wl[ol] = f2bf(w - bf2f(hi));
}

// ---------------------------------------------------------------------------
// Merge-GEMM fold (coalesced): E'[r][k] = sum_oc W1b[r][oc]*Wm[oc][k], stored
// at permuted col p = ((k&3)<<6)|(k>>2); beff[r] += geff[r]*(W1b·bm)[r].
// ---------------------------------------------------------------------------
__global__ void prep_fold(const float* __restrict__ W1, const float* __restrict__ Wm,
                          const float* __restrict__ bm,
                          bf16* __restrict__ Wbf, float* __restrict__ bias)
{
  int l = blockIdx.y;
  int r0 = blockIdx.x * 8;
  int k = threadIdx.x;
  __shared__ float w1b[8][256];
  for (int j = threadIdx.x; j < 2048; j += 256)
    w1b[j >> 8][j & 255] = W1[(size_t)l * 262144 + (r0 + (j >> 8)) * 512 + 256 + (j & 255)];
  __syncthreads();
  float acc[8] = {0.f, 0.f, 0.f, 0.f, 0.f, 0.f, 0.f, 0.f};
  const float* wmrow = Wm + (size_t)l * 65536 + k;
  for (int oc = 0; oc < 256; oc++) {
    float wv = wmrow[oc * 256];               // coalesced across threads
    #pragma unroll
    for (int j = 0; j < 8; j++) acc[j] += w1b[j][oc] * wv;  // LDS broadcast
  }
  int p = ((k & 3) << 6) | (k >> 2);          // inv-perm: perm(p) == k
  bf16* wl = Wbf + (size_t)l * 1310720;
  #pragma unroll
  for (int j = 0; j < 8; j++) {
    unsigned short hi = f2bf(acc[j]);
    wl[524288 + (size_t)(r0 + j) * 512 + 256 + p] = hi;
    wl[786432 + (size_t)(r0 + j) * 512 + 256 + p] = f2bf(acc[j] - bf2f(hi));
  }
  if (threadIdx.x < 8) {
    int j = threadIdx.x;
    float d = 0.f;
    for (int oc = 0; oc < 256; oc++) d += w1b[j][oc] * bm[l * 256 + oc];
    float ge = bias[l * 2304 + 1024 + r0 + j];
    bias[l * 2304 + 1536 + r0 + j] += ge * d;   // unique writer per row
  }
}

// ---------------------------------------------------------------------------
__global__ void transpose_in(const float* __restrict__ s0, const float* __restrict__ s1,
                             float* __restrict__ Dm, bf16* __restrict__ Hin,
                             bf16* __restrict__ XMl)
{
  __shared__ float t[32][33];
  int db = blockIdx.z;
  int dsc = db >> 1, bi = db & 1;
  const float* src = dsc ? s1 : s0;
  int n0 = blockIdx.x * 32, d0 = blockIdx.y * 32;
  int tx = threadIdx.x, ty = threadIdx.y;
  #pragma unroll
  for (int i = 0; i < 32; i += 8)
    t[ty + i][tx] = src[(size_t)(bi * 256 + d0 + ty + i) * 2048 + n0 + tx];
  __syncthreads();
  #pragma unroll
  for (int i = 0; i < 32; i += 8) {
    size_t xi = (size_t)db * 2048 + n0 + ty + i;
    float v = t[tx][ty + i];
    Dm[xi * 256 + d0 + tx] = v;
    unsigned short hi, lo;
    tsplit(v, hi, lo);
    Hin[xi * 512 + d0 + tx] = hi;
    XMl[xi * 512 + d0 + tx] = lo;
  }
}

__global__ void transpose_out(const float* __restrict__ Dm, float* __restrict__ out)
{
  __shared__ float t[32][33];
  int db = blockIdx.z;
  int n0 = blockIdx.x * 32, d0 = blockIdx.y * 32;
  int tx = threadIdx.x, ty = threadIdx.y;
  #pragma unroll
  for (int i = 0; i < 32; i += 8)
    t[ty + i][tx] = Dm[((size_t)db * 2048 + n0 + ty + i) * 256 + d0 + tx];
  __syncthreads();
  #pragma unroll
  for (int i = 0; i < 32; i += 8)
    out[(size_t)(db * 256 + d0 + ty + i) * 2048 + n0 + tx] = t[tx][ty + i];
}

// ---------------------------------------------------------------------------
// 3-term split GEMM (round-12 structure): tile 128xNT, BK=32, 4 waves,
// double-buffered global_load_lds, counted vmcnt + raw bars, sigma-swizzle.
// ---------------------------------------------------------------------------
DEVFN int gsw2(int row, int g) { return row * 32 + (((g ^ (row >> 1)) & 3) << 3); }

template<int EPI, int NT>
__global__ __launch_bounds__(256, (NT == 128) ? 2 : 3) void gemm3(
    const bf16* __restrict__ Ah, int lda,
    const bf16* __restrict__ Al, int ldal,
    const bf16* __restrict__ Wh, const bf16* __restrict__ Wl, int K,
    const float* __restrict__ b0, const float* __restrict__ b1,
    bf16* __restrict__ o0, bf16* __restrict__ o1,
    bf16* __restrict__ o2, bf16* __restrict__ o3,
    bf16* __restrict__ o4, bf16* __restrict__ o5,
    float* __restrict__ of)
{
  constexpr int NFR = NT / 32;
  __shared__ bf16 AsH[2][4096];
  __shared__ bf16 AsL[2][4096];
  __shared__ bf16 BsH[2][NT * 32];
  __shared__ bf16 BsL[2][NT * 32];
  int tid = threadIdx.x, lane = tid & 63, wid = tid >> 6;
  int wr = wid >> 1, wc = wid & 1;
  int m0 = blockIdx.x * 128, n0 = blockIdx.y * NT;

  int lrow = lane >> 2;
  int g4 = (((lane & 3) ^ (lane >> 3)) & 3) << 3;
  const bf16* A0h = Ah + (size_t)(m0 + wid * 16 + lrow) * lda + g4;
  const bf16* A0l = Al + (size_t)(m0 + wid * 16 + lrow) * ldal + g4;
  const bf16* B0h = Wh + (size_t)(n0 + wid * 16 + lrow) * K + g4;
  const bf16* B0l = Wl + (size_t)(n0 + wid * 16 + lrow) * K + g4;
  size_t a64h = (size_t)64 * lda, a64l = (size_t)64 * ldal, b64 = (size_t)64 * K;

  auto issue = [&](int k0, int b) {
    gll16(A0h + k0, &AsH[b][wid * 512]);
    gll16(A0h + a64h + k0, &AsH[b][2048 + wid * 512]);
    gll16(A0l + k0, &AsL[b][wid * 512]);
    gll16(A0l + a64l + k0, &AsL[b][2048 + wid * 512]);
    gll16(B0h + k0, &BsH[b][wid * 512]);
    gll16(B0l + k0, &BsL[b][wid * 512]);
    if constexpr (NT == 128) {
      gll16(B0h + b64 + k0, &BsH[b][2048 + wid * 512]);
      gll16(B0l + b64 + k0, &BsL[b][2048 + wid * 512]);
    }
  };

  f32x4 zero = {0.f, 0.f, 0.f, 0.f};
  f32x4 acc[4][NFR];
  #pragma unroll
  for (int i = 0; i < 4; i++)
    #pragma unroll
    for (int j = 0; j < NFR; j++) acc[i][j] = zero;

  int fr = lane & 15, g = lane >> 4;
  int cb = wc * (NT / 2);
  int nk = K >> 5;

  issue(0, 0);
  for (int ks = 0; ks < nk; ks++) {
    int cur = ks & 1;
    if (ks + 1 < nk) {
      issue((ks + 1) << 5, cur ^ 1);
      if constexpr (NT == 128) VMW(8); else VMW(6);
    } else {
      VMW(0);
    }
    RBAR(); SCHB();
    bf16x8 afh[4], afl[4], bfh[NFR], bfl[NFR];
    #pragma unroll
    for (int i = 0; i < 4; i++) {
      afh[i] = *(const bf16x8*)(&AsH[cur][gsw2(wr * 64 + i * 16 + fr, g)]);
      afl[i] = *(const bf16x8*)(&AsL[cur][gsw2(wr * 64 + i * 16 + fr, g)]);
    }
    #pragma unroll
    for (int i = 0; i < NFR; i++) {
      bfh[i] = *(const bf16x8*)(&BsH[cur][gsw2(cb + i * 16 + fr, g)]);
      bfl[i] = *(const bf16x8*)(&BsL[cur][gsw2(cb + i * 16 + fr, g)]);
    }
    #pragma unroll
    for (int mi = 0; mi < 4; mi++)
      #pragma unroll
      for (int ni = 0; ni < NFR; ni++) {
        acc[mi][ni] = MFMA_BF16(afh[mi], bfh[ni], acc[mi][ni]);
        acc[mi][ni] = MFMA_BF16(afl[mi], bfh[ni], acc[mi][ni]);
        acc[mi][ni] = MFMA_BF16(afh[mi], bfl[ni], acc[mi][ni]);
      }
    RBAR();
  }

  #pragma unroll
  for (int mi = 0; mi < 4; mi++) {
    #pragma unroll
    for (int ni = 0; ni < NFR; ni++) {
      int mrow = m0 + wr * 64 + mi * 16 + ((lane >> 4) << 2);
      int ocol = n0 + cb + ni * 16 + fr;
      if constexpr (EPI == 0) {          // fused QKV
        float bb = b0[ocol];
        if (ocol < 512) {
          bf16* Dh = (ocol < 256) ? o0 : o2;
          bf16* Dl = (ocol < 256) ? o1 : o3;
          int oo = ocol & 255;
          #pragma unroll
          for (int r = 0; r < 4; r++) {
            unsigned short hi, lo;
            tsplit(acc[mi][ni][r] + bb, hi, lo);
            Dh[(size_t)(mrow + r) * 256 + oo] = hi;
            Dl[(size_t)(mrow + r) * 256 + oo] = lo;
          }
        } else {
          int c = ocol - 512;
          int dbi = mrow >> 11, nn = mrow & 2047;
          u16x4 ph, pl;
          #pragma unroll
          for (int r = 0; r < 4; r++) {
            unsigned short hi, lo;
            tsplit(acc[mi][ni][r] + bb, hi, lo);
            ph[r] = hi; pl[r] = lo;
          }
          *(u16x4*)(&o4[((size_t)dbi * 256 + c) * 2048 + nn]) = ph;
          *(u16x4*)(&o5[((size_t)dbi * 256 + c) * 2048 + nn]) = pl;
        }
      } else if constexpr (EPI == 3) {   // BN+ReLU hi+lo
        float ge = b0[ocol], be = b1[ocol];
        #pragma unroll
        for (int r = 0; r < 4; r++) {
          unsigned short hi, lo;
          tsplit(fmaxf(ge * acc[mi][ni][r] + be, 0.f), hi, lo);
          o0[(size_t)(mrow + r) * 512 + ocol] = hi;
          o1[(size_t)(mrow + r) * 512 + ocol] = lo;
        }
      } else {                           // EPI 4: residual
        float bb = b0[ocol];
        #pragma unroll
        for (int r = 0; r < 4; r++) {
          size_t ix = (size_t)(mrow + r) * 256 + ocol;
          float d = of[ix] + acc[mi][ni][r] + bb;
          of[ix] = d;
          unsigned short hi, lo;
          tsplit(d, hi, lo);
          o0[(size_t)(mrow + r) * 512 + ocol] = hi;
          o1[(size_t)(mrow + r) * 512 + ocol] = lo;
        }
      }
    }
  }
}

// ---------------------------------------------------------------------------
// Flash attention, SWAPPED QK^T: sacc = mfma(K, Q) -> S[key][q=lane&15].
// Each lane owns one q-row: softmax max/sum = local ops + 2 shfl_xor;
// mrun/lrun scalars; P stored to LDS in [q][key] layout with packed b32
// writes (pairs of consecutive keys); PV A-frag reads unchanged.
// Split-KV (2 halves), 8 waves x 16 rows, 3-phase pipeline, defer-max.
// ---------------------------------------------------------------------------
DEVFN int swz(int row, int col) { return row * 64 + (col ^ ((row & 7) << 3)); }

__global__ __launch_bounds__(512, 4) void attn3s(
    const bf16* __restrict__ Qh, const bf16* __restrict__ Ql,
    const bf16* __restrict__ Kh, const bf16* __restrict__ Kl,
    const bf16* __restrict__ Vth, const bf16* __restrict__ Vtl,
    float* __restrict__ Pacc, float* __restrict__ Ml, int cross)
{
  __shared__ bf16 Ksh[64 * 64];
  __shared__ bf16 Ksl[64 * 64];
  __shared__ bf16 Vsh[64 * 64];
  __shared__ bf16 Vsl[64 * 64];
  __shared__ bf16 Psh[8][1024];
  __shared__ bf16 Psl[8][1024];
  int tid = threadIdx.x, lane = tid & 63, w = tid >> 6;
  int inst = blockIdx.y;
  int half = blockIdx.z;
  int db = inst >> 2, hd = inst & 3;
  int dsc = db >> 1, bi = db & 1;
  int sdb = (cross ? (1 - dsc) : dsc) * 2 + bi;
  size_t xq = (size_t)db * 2048;
  size_t xs = (size_t)sdb * 2048 + half * 1024;
  int n0 = blockIdx.x * 128;

  int fr = lane & 15, g = lane >> 4, kof = g << 3;

  // Q fragments hi/lo: direct global -> registers (row q = w*16 + fr)
  bf16x8 aqh[2], aql[2];
  #pragma unroll
  for (int kf = 0; kf < 2; kf++) {
    size_t gx = (xq + n0 + w * 16 + fr) * 256 + hd * 64 + kf * 32 + kof;
    aqh[kf] = *(const bf16x8*)(Qh + gx);
    aql[kf] = *(const bf16x8*)(Ql + gx);
  }

  f32x4 zero = {0.f, 0.f, 0.f, 0.f};
  f32x4 oacc[4];
  #pragma unroll
  for (int ni = 0; ni < 4; ni++) oacc[ni] = zero;
  float mrun = -3.0e38f, lrun = 0.f;   // per-lane: q = lane&15

  int lrow = lane >> 3;
  int g8 = ((lane & 7) ^ (lrow & 7)) << 3;
  int krow = w * 8 + lrow;
  const bf16* Ksrc_h = Kh + (xs + krow) * 256 + hd * 64 + g8;
  const bf16* Ksrc_l = Kl + (xs + krow) * 256 + hd * 64 + g8;
  const bf16* Vsrc_h = Vth + ((size_t)sdb * 256 + hd * 64 + krow) * 2048 + half * 1024 + g8;
  const bf16* Vsrc_l = Vtl + ((size_t)sdb * 256 + hd * 64 + krow) * 2048 + half * 1024 + g8;
  bf16* LKh = Ksh + w * 512;
  bf16* LKl = Ksl + w * 512;
  bf16* LVh = Vsh + w * 512;
  bf16* LVl = Vsl + w * 512;

  gll16(Ksrc_h, LKh);
  gll16(Ksrc_l, LKl);
  gll16(Vsrc_h, LVh);
  gll16(Vsrc_l, LVl);

  for (int t = 0; t < 16; t++) {
    VMW(4);            // K(t) landed; V(t) loads stay in flight
    RBAR(); SCHB();

    // ---- QK^T swapped: sacc[ni] = S[key = ni*16+4g+r][q = fr] ----
    f32x4 sacc[4];
    #pragma unroll
    for (int ni = 0; ni < 4; ni++) sacc[ni] = zero;
    #pragma unroll
    for (int kf = 0; kf < 2; kf++) {
      #pragma unroll
      for (int ni = 0; ni < 4; ni++) {
        bf16x8 bkh = *(const bf16x8*)(&Ksh[swz(ni * 16 + fr, kf * 32 + kof)]);
        bf16x8 bkl = *(const bf16x8*)(&Ksl[swz(ni * 16 + fr, kf * 32 + kof)]);
        sacc[ni] = MFMA_BF16(bkh, aqh[kf], sacc[ni]);
        sacc[ni] = MFMA_BF16(bkh, aql[kf], sacc[ni]);
        sacc[ni] = MFMA_BF16(bkl, aqh[kf], sacc[ni]);
      }
    }

    // ---- softmax, q local per lane: cheap defer-max check ----
    float tml = fmaxf(fmaxf(fmaxf(sacc[0][0], sacc[0][1]), fmaxf(sacc[0][2], sacc[0][3])),
               fmaxf(fmaxf(fmaxf(sacc[1][0], sacc[1][1]), fmaxf(sacc[1][2], sacc[1][3])),
               fmaxf(fmaxf(fmaxf(sacc[2][0], sacc[2][1]), fmaxf(sacc[2][2], sacc[2][3])),
                     fmaxf(fmaxf(sacc[3][0], sacc[3][1]), fmaxf(sacc[3][2], sacc[3][3])))));
    bool need = (tml > mrun + 8.0f);
    if (__ballot(need)) {
      float tm = fmaxf(tml, __shfl_xor(tml, 16));
      tm = fmaxf(tm, __shfl_xor(tm, 32));
      float mn = fmaxf(mrun, tm);
      float s = exp2f(mrun - mn);
      mrun = mn;
      lrun *= s;
      // oacc rows are q' = 4g + r; fetch s(q') from lane q' (group 0)
      #pragma unroll
      for (int r = 0; r < 4; r++) {
        float sr = __shfl(s, (g << 2) + r);
        #pragma unroll
        for (int ni = 0; ni < 4; ni++) oacc[ni][r] *= sr;
      }
    }
    float sum = 0.f;
    #pragma unroll
    for (int ni = 0; ni < 4; ni++)
      #pragma unroll
      for (int r = 0; r < 4; r++) {
        float pv = exp2f(sacc[ni][r] - mrun);
        sacc[ni][r] = pv;
        sum += pv;
      }
    sum += __shfl_xor(sum, 16);
    sum += __shfl_xor(sum, 32);
    lrun += sum;

    VMW(0);            // V(t) landed
    RBAR(); SCHB();

    if (t + 1 < 16) {  // K(t+1) flies under P-store + PV
      gll16(Ksrc_h + (size_t)(t + 1) * 16384, LKh);
      gll16(Ksrc_l + (size_t)(t + 1) * 16384, LKl);
    }

    // ---- P -> LDS, [q][key] layout, packed pair writes ----
    bf16* Pwh = &Psh[w][0];
    bf16* Pwl = &Psl[w][0];
    #pragma unroll
    for (int ni = 0; ni < 4; ni++) {
      #pragma unroll
      for (int rr = 0; rr < 2; rr++) {
        unsigned short h0, l0, h1, l1;
        tsplit(sacc[ni][2 * rr], h0, l0);
        tsplit(sacc[ni][2 * rr + 1], h1, l1);
        int key = ni * 16 + (g << 2) + 2 * rr;
        int off = swz(fr, key);
        *(unsigned*)(&Pwh[off]) = (unsigned)h0 | ((unsigned)h1 << 16);
        *(unsigned*)(&Pwl[off]) = (unsigned)l0 | ((unsigned)l1 << 16);
      }
    }

    // ---- PV (3-term); A-frag reads from [q][key] LDS (unchanged addrs) ----
    #pragma unroll
    for (int kf = 0; kf < 2; kf++) {
      bf16x8 pah = *(const bf16x8*)(&Pwh[swz(fr, kf * 32 + kof)]);
      bf16x8 pal = *(const bf16x8*)(&Pwl[swz(fr, kf * 32 + kof)]);
      #pragma unroll
      for (int ni = 0; ni < 4; ni++) {
        bf16x8 bvh = *(const bf16x8*)(&Vsh[swz(ni * 16 + fr, kf * 32 + kof)]);
        bf16x8 bvl = *(const bf16x8*)(&Vsl[swz(ni * 16 + fr, kf * 32 + kof)]);
        oacc[ni] = MFMA_BF16(pah, bvh, oacc[ni]);
        oacc[ni] = MFMA_BF16(pal, bvh, oacc[ni]);
        oacc[ni] = MFMA_BF16(pah, bvl, oacc[ni]);
      }
    }

    RBAR();
    if (t + 1 < 16) {  // V(t+1) flies under next QK^T + softmax
      gll16(Vsrc_h + (t + 1) * 64, LVh);
      gll16(Vsrc_l + (t + 1) * 64, LVl);
    }
  }

  // store unnormalized partial O (fp32, rows q' = 4g+r) + per-row (m, l)
  float* Pb = Pacc + (size_t)half * 8192 * 256;
  #pragma unroll
  for (int r = 0; r < 4; r++) {
    int nrow = n0 + w * 16 + (g << 2) + r;
    size_t row = xq + nrow;
    #pragma unroll
    for (int ni = 0; ni < 4; ni++)
      Pb[row * 256 + hd * 64 + ni * 16 + fr] = oacc[ni][r];
  }
  if (lane < 16) {     // lane holds (mrun, lrun) for q = lane
    size_t row = xq + n0 + w * 16 + lane;
    float* mp = Ml + ((row * 4 + hd) << 2) + half * 2;
    mp[0] = mrun;
    mp[1] = lrun;
  }
}

// ---------------------------------------------------------------------------
// Combine the two KV halves; writes O directly into Hin/XMl cols 256:512.
// ---------------------------------------------------------------------------
__global__ __launch_bounds__(256) void attn_combine(
    const float* __restrict__ Pacc, const float* __restrict__ Ml,
    bf16* __restrict__ Hin, bf16* __restrict__ XMl)
{
  int tid = threadIdx.x, lane = tid & 63, w = tid >> 6;
  size_t row = (size_t)blockIdx.x * 4 + w;
  int hd = lane >> 4;
  int c0 = lane * 4;
  const float* mp = Ml + ((row * 4 + hd) << 2);
  float ma = mp[0], la = mp[1], mb = mp[2], lb = mp[3];
  float m = fmaxf(ma, mb);
  float wa = exp2f(ma - m), wb = exp2f(mb - m);
  float inv = 1.0f / (la * wa + lb * wb);
  wa *= inv; wb *= inv;
  f32x4 pa = *(const f32x4*)(Pacc + row * 256 + c0);
  f32x4 pb = *(const f32x4*)(Pacc + (size_t)8192 * 256 + row * 256 + c0);
  u16x4 vh, vl;
  #pragma unroll
  for (int r = 0; r < 4; r++) {
    unsigned short hi, lo;
    tsplit(pa[r] * wa + pb[r] * wb, hi, lo);
    vh[r] = hi; vl[r] = lo;
  }
  *(u16x4*)(Hin + row * 512 + 256 + c0) = vh;
  *(u16x4*)(XMl + row * 512 + 256 + c0) = vl;
}

// ---------------------------------------------------------------------------
extern "C" void kernel_launch(void* const* d_in, const int* in_sizes, int n_in,
                              void* d_out, int out_size, void* d_ws, size_t ws_size,
                              hipStream_t stream)
{
  (void)in_sizes; (void)n_in; (void)out_size; (void)ws_size;
  const float* desc0 = (const float*)d_in[0];
  const float* desc1 = (const float*)d_in[1];
  const float* Wq = (const float*)d_in[2];
  const float* bq = (const float*)d_in[3];
  const float* Wk = (const float*)d_in[4];
  const float* bk = (const float*)d_in[5];
  const float* Wv = (const float*)d_in[6];
  const float* bv = (const float*)d_in[7];
  const float* Wm = (const float*)d_in[8];
  const float* bm = (const float*)d_in[9];
  const float* W1 = (const float*)d_in[10];
  const float* b1 = (const float*)d_in[11];
  const float* gm = (const float*)d_in[12];
  const float* bt = (const float*)d_in[13];
  const float* W2 = (const float*)d_in[14];
  const float* b2 = (const float*)d_in[15];
  float* out = (float*)d_out;

  char* ws = (char*)d_ws;
  bf16*  Wbf  = (bf16*)(ws + 0);            //  31,457,280
  float* bias = (float*)(ws + 31457280);    //     110,592
  float* Dm   = (float*)(ws + 31567872);    //  16,777,216  fp32 master [xi,256]
  bf16*  Hin  = (bf16*)(ws + 48345088);     //  16,777,216  [xi,512] = xh | O_h
  bf16*  XMl  = (bf16*)(ws + 65122304);     //  16,777,216  [xi,512] = xl | O_l
  bf16*  Qh   = (bf16*)(ws + 81899520);     //   8,388,608
  bf16*  Ql   = (bf16*)(ws + 90288128);     //   8,388,608
  bf16*  Kh   = (bf16*)(ws + 98676736);     //   8,388,608
  bf16*  Kl   = (bf16*)(ws + 107065344);    //   8,388,608
  bf16*  Vth  = (bf16*)(ws + 115453952);    //   8,388,608  [db,256,2048]
  bf16*  Vtl  = (bf16*)(ws + 123842560);    //   8,388,608
  float* Pacc = (float*)(ws + 132231168);   //  16,777,216  [2][8192][256] fp32
  float* Ml   = (float*)(ws + 149008384);   //     524,288  [8192][4][4]
  // end: 149,532,672
  bf16*  Hbh  = Qh;                         // alias Qh+Ql (disjoint in time)
  bf16*  Hbl  = Kh;                         // alias Kh+Kl

  prep_weights<<<dim3(2313, 12), 256, 0, stream>>>(Wq, bq, Wk, bk, Wv, bv, Wm, bm,
                                                   W1, b1, gm, bt, W2, b2, Wbf, bias);
  prep_fold<<<dim3(64, 12), 256, 0, stream>>>(W1, Wm, bm, Wbf, bias);
  transpose_in<<<dim3(64, 8, 4), dim3(32, 8), 0, stream>>>(desc0, desc1, Dm, Hin, XMl);

  for (int l = 0; l < NL; l++) {
    const bf16* wl = Wbf + (size_t)l * 1310720;
    const float* bl = bias + l * 2304;
    int cross = l & 1;
    // fused QKV (Q pre-scaled by log2e/8)
    gemm3<0, 128><<<dim3(64, 6), 256, 0, stream>>>(Hin, 512, XMl, 512,
        wl, wl + 196608, 256, bl, nullptr,
        Qh, Ql, Kh, Kl, Vth, Vtl, nullptr);
    // split-KV attention + combine (combine writes O into Hin/XMl msg-half)
    attn3s<<<dim3(16, 16, 2), 512, 0, stream>>>(Qh, Ql, Kh, Kl, Vth, Vtl,
                                                Pacc, Ml, cross);
    attn_combine<<<2048, 256, 0, stream>>>(Pacc, Ml, Hin, XMl);
    // MLP1 (merge folded in: A = [x | O], W1eff) + BN + ReLU
    gemm3<3, 128><<<dim3(64, 4), 256, 0, stream>>>(Hin, 512, XMl, 512,
        wl + 524288, wl + 786432, 512, bl + 1024, bl + 1536,
        Hbh, Hbl, nullptr, nullptr, nullptr, nullptr, nullptr);
    // MLP2 + residual
    gemm3<4, 64><<<dim3(64, 4), 256, 0, stream>>>(Hbh, 512, Hbl, 512,
        wl + 1048576, wl + 1179648, 512, bl + 2048, nullptr,
        Hin, XMl, nullptr, nullptr, nullptr, nullptr, Dm);
  }
  transpose_out<<<dim3(64, 8, 4), dim3(32, 8), 0, stream>>>(Dm, out);
}